// Round 1
// baseline (571.514 us; speedup 1.0000x reference)
//
#include <hip/hip_runtime.h>
#include <hip/hip_cooperative_groups.h>
#include <cstdint>
#include <cstddef>

namespace cg = cooperative_groups;

#define N_TOT   147456      // 9*128*128
#define K_PRE   6000
#define K_POST  300
#define CAP     32768       // candidate cap (expected ~9.2K)
#define MW      188         // 6016 bits per mask row -> 188 u32 words
#define ROWS_PAD 6016
#define NCHUNK  94
#define CT      128         // k_mask columns per tile
#define ROWB    24
#define COLB    47
#define NTILE   (ROWB*COLB) // 1128 mask tiles
#define G       16
#define NBLK    576         // one block per 256 anchors; fully co-resident (<=4/CU)

// workspace offsets (256-aligned, keys slot retained for the fallback path)
#define OFF_HIST 0u
#define OFF_META 16640u          // 16384 + 256
#define OFF_KEYS 16896u          // N_TOT*4 = 589824
#define OFF_CAND 606720u         // CAP*8 = 262144
#define OFF_P    868864u         // K_PRE*16 = 96000
#define OFF_YK   964864u         // K_PRE*8 = 48000 -> pad 48128
#define OFF_OP   1012992u
#define OFF_Q    1108992u
#define OFF_BND  1204992u        // K_PRE*4 = 24000 -> pad 24064
#define OFF_MASK 1229056u        // ROWS_PAD*MW*4 = 4524032

__constant__ float c_sizes[9] = {4.f,8.f,12.f,16.f,24.f,32.f,48.f,64.f,96.f};

// Bit-exact replication of reference box math (anchor + delta, clip).
__device__ __forceinline__ void compute_box(int idx, const float* __restrict__ deltas,
                                            float& px1, float& py1, float& pw, float& ph) {
    int a   = idx >> 14;
    int rem = idx & 16383;
    int h   = rem >> 7;
    int w   = rem & 127;
    float s    = c_sizes[a];
    float half = s * 0.5f;
    const float4 d = *(const float4*)(deltas + (size_t)a * 65536 + (size_t)rem * 4);
    float b0 = (((float)h + 0.5f) - half) + d.x;
    float b1 = (((float)w + 0.5f) - half) + d.y;
    float b2 = s + d.z;
    float b3 = s + d.w;
    b0 = fmaxf(b0, 0.0f); b1 = fmaxf(b1, 0.0f);
    b2 = fmaxf(b2, 0.0f); b3 = fmaxf(b3, 0.0f);
    float x1 = b0, y1 = b1;
    float x2 = b0 + b2, y2 = b1 + b3;
    x1 = fminf(x1, 128.0f); y1 = fminf(y1, 128.0f);
    x2 = fminf(x2, 128.0f); y2 = fminf(y2, 128.0f);
    px1 = x1; py1 = y1; pw = x2 - x1; ph = y2 - y1;
}

__device__ __forceinline__ uint32_t waveReduceSum(uint32_t v) {
    #pragma unroll
    for (int o = 32; o > 0; o >>= 1) v += __shfl_xor(v, o, 64);
    return v;
}

// ============================================================================
// Fused cooperative mega-kernel: all 6 stages + zeroing in ONE dispatch.
// Grid = 576 blocks x 256 threads, co-resident (launch_bounds caps VGPR=128
// -> 4 blocks/CU -> 1024 capacity). Phase code is verbatim from the verified
// split kernels; grid.sync() replaces kernel boundaries.
// ============================================================================
__global__ void __launch_bounds__(256, 4) mega(const float* __restrict__ scores,
                                               const float* __restrict__ deltas,
                                               float* __restrict__ out,
                                               char* __restrict__ ws) {
    __shared__ __align__(16) char smem[17664];
    cg::grid_group grid = cg::this_grid();

    uint32_t* hist = (uint32_t*)(ws + OFF_HIST);
    uint32_t* meta = (uint32_t*)(ws + OFF_META);
    uint64_t* cand = (uint64_t*)(ws + OFF_CAND);
    float4*   P    = (float4*)(ws + OFF_P);
    uint64_t* yk   = (uint64_t*)(ws + OFF_YK);
    float4*   OP   = (float4*)(ws + OFF_OP);
    float4*   Q    = (float4*)(ws + OFF_Q);
    float*    Bnd  = (float*)(ws + OFF_BND);
    uint32_t* mask = (uint32_t*)(ws + OFF_MASK);

    const int tid = threadIdx.x;
    const int bid = blockIdx.x;
    const int wave = tid >> 6, lane = tid & 63;

    // ---- phase Z: zero hist + meta (replaces hipMemsetAsync) ----
    if (bid < 16) hist[bid * 256 + tid] = 0u;
    if (bid == 16 && tid < 16) meta[tid] = 0u;
    grid.sync();

    // ---- phase 1: keys + histogram (key kept in a REGISTER; no keys array) ----
    uint32_t myKey;
    {
        uint32_t* lh = (uint32_t*)smem;
        for (int i = tid; i < 4096; i += 256) lh[i] = 0u;
        __syncthreads();
        int idx = bid * 256 + tid;
        float px1, py1, pw, ph;
        compute_box(idx, deltas, px1, py1, pw, ph);
        bool keep = (pw >= 3.0f) && (ph >= 3.0f);
        float sc = scores[idx];
        myKey = keep ? __float_as_uint(sc) : 0u;
        atomicAdd(&lh[myKey >> 20], 1u);
        __syncthreads();
        for (int i = tid; i < 4096; i += 256) {
            uint32_t v = lh[i];
            if (v) atomicAdd(&hist[i], v);
        }
    }
    grid.sync();

    // ---- phase 2: findbin (parallel suffix scan) + compact ----
    {
        uint32_t* lh  = (uint32_t*)smem;
        uint32_t* seg = (uint32_t*)(smem + 16384);
        uint32_t* bsh = (uint32_t*)(smem + 16384 + 1024);
        for (int i = tid; i < 4096; i += 256) lh[i] = hist[i];
        __syncthreads();
        uint32_t s = 0;
        #pragma unroll
        for (int q = 0; q < 16; q++) s += lh[tid * 16 + q];
        seg[tid] = s;
        __syncthreads();
        for (int off = 1; off < 256; off <<= 1) {
            uint32_t v = seg[tid];
            if (tid + off < 256) v += seg[tid + off];
            __syncthreads();
            seg[tid] = v;
            __syncthreads();
        }
        uint32_t St  = seg[tid];
        uint32_t St1 = (tid < 255) ? seg[tid + 1] : 0u;
        if (St >= K_PRE && St1 < K_PRE) {
            uint32_t c2 = St1;
            uint32_t bstar = 0u;
            for (int q = 15; q >= 0; q--) {
                c2 += lh[tid * 16 + q];
                if (c2 >= K_PRE) { bstar = (uint32_t)(tid * 16 + q); break; }
            }
            bsh[0] = bstar;
        }
        if (tid == 0 && seg[0] < K_PRE) bsh[0] = 0u;
        __syncthreads();
        uint32_t bstar = bsh[0];
        int idx = bid * 256 + tid;
        if ((myKey >> 20) >= bstar) {
            uint32_t pos = atomicAdd(meta + 1, 1u);
            if (pos < CAP) cand[pos] = ((uint64_t)myKey << 32) | (uint32_t)(~(uint32_t)idx);
        }
    }
    grid.sync();

    // ---- phase 3: rank-by-count over candidates -> P, yk ----
    {
        uint32_t (*part)[G] = (uint32_t (*)[G])smem;
        uint32_t C = meta[1];
        if (C > CAP) C = CAP;
        uint32_t nGroups = (C + G - 1) / G;
        for (uint32_t g = bid; g < nGroups; g += NBLK) {
            uint32_t b = g * G;
            uint64_t m[G];
            uint32_t cnt[G];
            #pragma unroll
            for (int q = 0; q < G; q++) {
                m[q] = (b + q < C) ? cand[b + q] : ~0ull;
                cnt[q] = 0u;
            }
            for (uint32_t j0 = 0; j0 < C; j0 += 1024) {
                uint32_t ja = j0 + tid, jb = ja + 256, jc = ja + 512, jd = ja + 768;
                uint64_t ka = (ja < C) ? cand[ja] : 0ull;
                uint64_t kb = (jb < C) ? cand[jb] : 0ull;
                uint64_t kc = (jc < C) ? cand[jc] : 0ull;
                uint64_t kd = (jd < C) ? cand[jd] : 0ull;
                #pragma unroll
                for (int q = 0; q < G; q++)
                    cnt[q] += (uint32_t)(ka > m[q]) + (uint32_t)(kb > m[q])
                            + (uint32_t)(kc > m[q]) + (uint32_t)(kd > m[q]);
            }
            #pragma unroll
            for (int q = 0; q < G; q++) cnt[q] = waveReduceSum(cnt[q]);
            if (lane == 0) {
                #pragma unroll
                for (int q = 0; q < G; q++) part[wave][q] = cnt[q];
            }
            __syncthreads();
            if (tid < G && b + tid < C) {
                uint32_t r = part[0][tid] + part[1][tid] + part[2][tid] + part[3][tid];
                if (r < K_PRE) {
                    int idx = (int)(~((uint32_t)cand[b + tid]));
                    float px1, py1, pw, ph;
                    compute_box(idx, deltas, px1, py1, pw, ph);
                    P[r] = make_float4(px1, py1, pw, ph);
                    float y2 = py1 + ph;
                    yk[r] = ((uint64_t)__float_as_uint(y2) << 32) | (uint32_t)(~r);
                }
            }
            __syncthreads();
        }
    }
    grid.sync();

    // ---- phase 4: stable y2-desc rank + epilogue (OP, Q, Bnd) ----
    if (bid < K_PRE / G) {
        uint32_t (*part)[G] = (uint32_t (*)[G])smem;
        uint32_t b = (uint32_t)bid * G;
        uint64_t m[G];
        uint32_t cnt[G];
        #pragma unroll
        for (int q = 0; q < G; q++) {
            m[q] = yk[b + q];
            cnt[q] = 0u;
        }
        for (uint32_t j0 = 0; j0 < K_PRE; j0 += 1024) {
            uint32_t ja = j0 + tid, jb = ja + 256, jc = ja + 512, jd = ja + 768;
            uint64_t ka = (ja < K_PRE) ? yk[ja] : 0ull;
            uint64_t kb = (jb < K_PRE) ? yk[jb] : 0ull;
            uint64_t kc = (jc < K_PRE) ? yk[jc] : 0ull;
            uint64_t kd = (jd < K_PRE) ? yk[jd] : 0ull;
            #pragma unroll
            for (int q = 0; q < G; q++)
                cnt[q] += (uint32_t)(ka > m[q]) + (uint32_t)(kb > m[q])
                        + (uint32_t)(kc > m[q]) + (uint32_t)(kd > m[q]);
        }
        #pragma unroll
        for (int q = 0; q < G; q++) cnt[q] = waveReduceSum(cnt[q]);
        if (lane == 0) {
            #pragma unroll
            for (int q = 0; q < G; q++) part[wave][q] = cnt[q];
        }
        __syncthreads();
        if (tid < G) {
            uint32_t r = part[0][tid] + part[1][tid] + part[2][tid] + part[3][tid];
            float4 p = P[b + tid];
            OP[r] = p;
            float x1 = p.x, y1 = p.y;
            float x2 = x1 + p.z, y2 = y1 + p.w;
            float area = fmaxf((x2 - x1) * (y2 - y1), 1e-6f);
            Q[r] = make_float4(x1, y1, x2, y2);
            const double Mc = (double)0.7f - 0x1.0p-25;
            double c = Mc * (double)area;       // exact
            float Bf = (float)c;
            if (!((double)Bf > c)) Bf = __int_as_float(__float_as_int(Bf) + 1);
            Bnd[r] = Bf;
        }
    }
    grid.sync();

    // ---- phase 5: suppression bitmask, tiled ----
    {
        float4* qs = (float4*)smem;
        float*  bs = (float*)(smem + CT * 16);
        for (uint32_t t = bid; t < NTILE; t += NBLK) {
            int bx = (int)(t % ROWB);
            int by = (int)(t / ROWB);
            int i  = bx * 256 + tid;
            int c0 = by * CT;
            int ncols = min(CT, K_PRE - c0);
            bool rowok = (i < K_PRE);
            float4 qi = rowok ? Q[i] : make_float4(0.f, 0.f, 0.f, 0.f);
            __syncthreads();     // protect qs/bs from previous iteration's readers
            for (int j = tid; j < ncols; j += 256) {
                qs[j] = Q[c0 + j];
                bs[j] = Bnd[c0 + j];
            }
            __syncthreads();
            int nw = (ncols + 31) >> 5;
            for (int w = 0; w < nw; w++) {
                uint32_t bits = 0u;
                int jb = w * 32;
                int jn = min(32, ncols - jb);
                #pragma unroll 8
                for (int b = 0; b < jn; b++) {
                    int j = jb + b;
                    float4 qj = qs[j];
                    float iw = fminf(qi.z, qj.z) - fmaxf(qi.x, qj.x) + 1.0f;
                    iw = fmaxf(iw, 0.0f);
                    float ih = fminf(qi.w, qj.w) - fmaxf(qi.y, qj.y) + 1.0f;
                    ih = fmaxf(ih, 0.0f);
                    float d = iw * ih;
                    bits |= (d >= bs[j]) ? (1u << b) : 0u;
                }
                if (rowok) {
                    int gj = c0 + jb;
                    uint32_t selfo = (uint32_t)(i - gj);
                    if (selfo < 32u) bits &= ~(1u << selfo);
                    mask[(size_t)i * MW + (gj >> 5)] = bits;
                }
            }
        }
    }
    grid.sync();

    // ---- phase 6: serial active scan + emit (block 0 only) ----
    if (bid == 0) {
        uint32_t* rem  = (uint32_t*)smem;        // 188
        uint32_t* sidx = rem + MW;               // 64
        uint32_t* svL  = sidx + 64;              // 188
        uint32_t* pref = svL + MW;               // 188
        uint32_t* nsSh = pref + MW;              // 1
        for (int i = tid; i < MW; i += 256) rem[i] = 0u;
        for (int i = tid; i < K_POST * 4; i += 256) out[i] = 0.0f;
        __syncthreads();
        uint2 mr = make_uint2(0u, 0u);
        if (tid < 64) mr = *(const uint2*)(mask + (size_t)tid * MW);
        for (int c = 0; c < NCHUNK; c++) {
            int base = c * 64;
            int rows = min(64, K_PRE - base);
            if (tid < 64) {
                uint64_t v = ~(((uint64_t)rem[2 * c + 1] << 32) | (uint64_t)rem[2 * c]);
                if (rows < 64) v &= ((1ull << rows) - 1ull);
                uint64_t work = v, surv = 0ull;
                while (work) {
                    int k = __ffsll((unsigned long long)work) - 1;
                    surv |= 1ull << k;
                    uint64_t rowk =
                        ((uint64_t)(uint32_t)__builtin_amdgcn_readlane((int)mr.y, k) << 32)
                      |  (uint64_t)(uint32_t)__builtin_amdgcn_readlane((int)mr.x, k);
                    work &= ~rowk;
                    work &= ~(1ull << k);
                }
                uint32_t ns = (uint32_t)__popcll(surv);
                if (tid == 0) {
                    svL[2 * c]     = (uint32_t)surv;
                    svL[2 * c + 1] = (uint32_t)(surv >> 32);
                    nsSh[0] = ns;
                }
                if ((surv >> tid) & 1ull) {
                    uint32_t pr = __popcll(surv & ((1ull << tid) - 1ull));
                    sidx[pr] = (uint32_t)(base + tid);
                }
                if (surv) {
                    uint32_t nsPad = (ns + 15u) & ~15u;
                    uint32_t first = (uint32_t)base +
                                     (uint32_t)(__ffsll((unsigned long long)surv) - 1);
                    if ((uint32_t)tid >= ns && (uint32_t)tid < nsPad) sidx[tid] = first;
                }
                if (c + 1 < NCHUNK)
                    mr = *(const uint2*)(mask + (size_t)(base + 64 + tid) * MW + 2 * (c + 1));
            }
            __syncthreads();
            int w = tid - 64;
            if (w >= 0 && w < MW) {
                uint32_t nsPad = (nsSh[0] + 15u) & ~15u;
                uint32_t acc = rem[w];
                for (uint32_t t2 = 0; t2 < nsPad; t2 += 16) {
                    uint32_t r[16];
                    #pragma unroll
                    for (int q = 0; q < 16; q++)
                        r[q] = mask[(size_t)sidx[t2 + q] * MW + w];
                    uint32_t o = 0u;
                    #pragma unroll
                    for (int q = 0; q < 16; q++) o |= r[q];
                    acc |= o;
                }
                rem[w] = acc;
            }
            __syncthreads();
        }
        if (tid < MW) {
            uint32_t vv = svL[tid] & ~rem[tid];
            if (tid == MW - 1) vv &= 0xFFFFu;
            rem[tid] = vv;
        }
        __syncthreads();
        if (tid == 0) {
            uint32_t run = 0;
            for (int w2 = 0; w2 < MW; w2++) { pref[w2] = run; run += (uint32_t)__popc(rem[w2]); }
        }
        __syncthreads();
        if (tid < MW) {
            uint32_t b = rem[tid];
            uint32_t r = pref[tid];
            int basebit = tid * 32;
            while (b && r < K_POST) {
                int bit = __ffs(b) - 1;
                b &= b - 1u;
                float4 pp = OP[basebit + bit];
                *(float4*)(out + (size_t)r * 4) = pp;
                r++;
            }
        }
    }
}

// ============================================================================
// Fallback split kernels (verbatim previous verified version) — used only if
// the cooperative launch is rejected by the runtime/graph capture.
// ============================================================================
__global__ void k_keys_hist(const float* __restrict__ scores, const float* __restrict__ deltas,
                            uint32_t* __restrict__ keys, uint32_t* __restrict__ hist) {
    __shared__ uint32_t lh[4096];
    for (int i = threadIdx.x; i < 4096; i += 256) lh[i] = 0u;
    __syncthreads();
    int idx = blockIdx.x * 256 + threadIdx.x;
    float px1, py1, pw, ph;
    compute_box(idx, deltas, px1, py1, pw, ph);
    bool keep = (pw >= 3.0f) && (ph >= 3.0f);
    float sc = scores[idx];
    uint32_t key = keep ? __float_as_uint(sc) : 0u;
    keys[idx] = key;
    atomicAdd(&lh[key >> 20], 1u);
    __syncthreads();
    for (int i = threadIdx.x; i < 4096; i += 256) {
        uint32_t v = lh[i];
        if (v) atomicAdd(&hist[i], v);
    }
}

__global__ void k_findbin_compact(const uint32_t* __restrict__ hist,
                                  const uint32_t* __restrict__ keys,
                                  uint64_t* __restrict__ cand, uint32_t* counter) {
    __shared__ uint32_t lh[4096];
    __shared__ uint32_t seg[256];
    __shared__ uint32_t bsh;
    for (int i = threadIdx.x; i < 4096; i += 256) lh[i] = hist[i];
    __syncthreads();
    uint32_t s = 0;
    #pragma unroll
    for (int q = 0; q < 16; q++) s += lh[threadIdx.x * 16 + q];
    seg[threadIdx.x] = s;
    __syncthreads();
    for (int off = 1; off < 256; off <<= 1) {
        uint32_t v = seg[threadIdx.x];
        if (threadIdx.x + off < 256) v += seg[threadIdx.x + off];
        __syncthreads();
        seg[threadIdx.x] = v;
        __syncthreads();
    }
    uint32_t St  = seg[threadIdx.x];
    uint32_t St1 = (threadIdx.x < 255) ? seg[threadIdx.x + 1] : 0u;
    if (St >= K_PRE && St1 < K_PRE) {
        uint32_t c2 = St1;
        uint32_t bstar = 0u;
        for (int q = 15; q >= 0; q--) {
            c2 += lh[threadIdx.x * 16 + q];
            if (c2 >= K_PRE) { bstar = (uint32_t)(threadIdx.x * 16 + q); break; }
        }
        bsh = bstar;
    }
    if (threadIdx.x == 0 && seg[0] < K_PRE) bsh = 0u;
    __syncthreads();
    uint32_t bstar = bsh;
    int idx = blockIdx.x * 256 + threadIdx.x;
    uint32_t key = keys[idx];
    if ((key >> 20) >= bstar) {
        uint32_t pos = atomicAdd(counter, 1u);
        if (pos < CAP) cand[pos] = ((uint64_t)key << 32) | (uint32_t)(~(uint32_t)idx);
    }
}

__global__ void __launch_bounds__(256) k_rank_props(
        const uint64_t* __restrict__ cand, const uint32_t* __restrict__ meta,
        const float* __restrict__ deltas,
        float4* __restrict__ P, uint64_t* __restrict__ yk) {
    __shared__ uint32_t part[4][G];
    uint32_t C = meta[1];
    if (C > CAP) C = CAP;
    uint32_t nGroups = (C + G - 1) / G;
    int tid  = threadIdx.x;
    int wave = tid >> 6, lane = tid & 63;
    for (uint32_t g = blockIdx.x; g < nGroups; g += gridDim.x) {
        uint32_t b = g * G;
        uint64_t m[G];
        uint32_t cnt[G];
        #pragma unroll
        for (int q = 0; q < G; q++) {
            m[q] = (b + q < C) ? cand[b + q] : ~0ull;
            cnt[q] = 0u;
        }
        for (uint32_t j0 = 0; j0 < C; j0 += 1024) {
            uint32_t ja = j0 + tid, jb = ja + 256, jc = ja + 512, jd = ja + 768;
            uint64_t ka = (ja < C) ? cand[ja] : 0ull;
            uint64_t kb = (jb < C) ? cand[jb] : 0ull;
            uint64_t kc = (jc < C) ? cand[jc] : 0ull;
            uint64_t kd = (jd < C) ? cand[jd] : 0ull;
            #pragma unroll
            for (int q = 0; q < G; q++)
                cnt[q] += (uint32_t)(ka > m[q]) + (uint32_t)(kb > m[q])
                        + (uint32_t)(kc > m[q]) + (uint32_t)(kd > m[q]);
        }
        #pragma unroll
        for (int q = 0; q < G; q++) cnt[q] = waveReduceSum(cnt[q]);
        if (lane == 0) {
            #pragma unroll
            for (int q = 0; q < G; q++) part[wave][q] = cnt[q];
        }
        __syncthreads();
        if (tid < G && b + tid < C) {
            uint32_t r = part[0][tid] + part[1][tid] + part[2][tid] + part[3][tid];
            if (r < K_PRE) {
                int idx = (int)(~((uint32_t)cand[b + tid]));
                float px1, py1, pw, ph;
                compute_box(idx, deltas, px1, py1, pw, ph);
                P[r] = make_float4(px1, py1, pw, ph);
                float y2 = py1 + ph;
                yk[r] = ((uint64_t)__float_as_uint(y2) << 32) | (uint32_t)(~r);
            }
        }
        __syncthreads();
    }
}

__global__ void __launch_bounds__(256) k_rank_y2(
        const uint64_t* __restrict__ ykey, const float4* __restrict__ P,
        float4* __restrict__ OP, float4* __restrict__ Q, float* __restrict__ Bnd) {
    __shared__ uint32_t part[4][G];
    int tid  = threadIdx.x;
    int wave = tid >> 6, lane = tid & 63;
    uint32_t b = blockIdx.x * G;
    uint64_t m[G];
    uint32_t cnt[G];
    #pragma unroll
    for (int q = 0; q < G; q++) {
        m[q] = ykey[b + q];
        cnt[q] = 0u;
    }
    for (uint32_t j0 = 0; j0 < K_PRE; j0 += 1024) {
        uint32_t ja = j0 + tid, jb = ja + 256, jc = ja + 512, jd = ja + 768;
        uint64_t ka = (ja < K_PRE) ? ykey[ja] : 0ull;
        uint64_t kb = (jb < K_PRE) ? ykey[jb] : 0ull;
        uint64_t kc = (jc < K_PRE) ? ykey[jc] : 0ull;
        uint64_t kd = (jd < K_PRE) ? ykey[jd] : 0ull;
        #pragma unroll
        for (int q = 0; q < G; q++)
            cnt[q] += (uint32_t)(ka > m[q]) + (uint32_t)(kb > m[q])
                    + (uint32_t)(kc > m[q]) + (uint32_t)(kd > m[q]);
    }
    #pragma unroll
    for (int q = 0; q < G; q++) cnt[q] = waveReduceSum(cnt[q]);
    if (lane == 0) {
        #pragma unroll
        for (int q = 0; q < G; q++) part[wave][q] = cnt[q];
    }
    __syncthreads();
    if (tid < G) {
        uint32_t r = part[0][tid] + part[1][tid] + part[2][tid] + part[3][tid];
        float4 p = P[b + tid];
        OP[r] = p;
        float x1 = p.x, y1 = p.y;
        float x2 = x1 + p.z, y2 = y1 + p.w;
        float area = fmaxf((x2 - x1) * (y2 - y1), 1e-6f);
        Q[r] = make_float4(x1, y1, x2, y2);
        const double Mc = (double)0.7f - 0x1.0p-25;
        double c = Mc * (double)area;
        float Bf = (float)c;
        if (!((double)Bf > c)) Bf = __int_as_float(__float_as_int(Bf) + 1);
        Bnd[r] = Bf;
    }
}

__global__ void __launch_bounds__(256) k_mask(const float4* __restrict__ Q,
                                              const float* __restrict__ Bnd,
                                              uint32_t* __restrict__ mask) {
    __shared__ float4 qs[CT];
    __shared__ float  bs[CT];
    int i  = blockIdx.x * 256 + threadIdx.x;
    int c0 = blockIdx.y * CT;
    int ncols = min(CT, K_PRE - c0);
    bool rowok = (i < K_PRE);
    float4 qi = rowok ? Q[i] : make_float4(0.f, 0.f, 0.f, 0.f);
    for (int j = threadIdx.x; j < ncols; j += 256) {
        qs[j] = Q[c0 + j];
        bs[j] = Bnd[c0 + j];
    }
    __syncthreads();
    int nw = (ncols + 31) >> 5;
    for (int w = 0; w < nw; w++) {
        uint32_t bits = 0u;
        int jb = w * 32;
        int jn = min(32, ncols - jb);
        #pragma unroll 8
        for (int b = 0; b < jn; b++) {
            int j = jb + b;
            float4 qj = qs[j];
            float iw = fminf(qi.z, qj.z) - fmaxf(qi.x, qj.x) + 1.0f;
            iw = fmaxf(iw, 0.0f);
            float ih = fminf(qi.w, qj.w) - fmaxf(qi.y, qj.y) + 1.0f;
            ih = fmaxf(ih, 0.0f);
            float d = iw * ih;
            bits |= (d >= bs[j]) ? (1u << b) : 0u;
        }
        if (rowok) {
            int gj = c0 + jb;
            uint32_t selfo = (uint32_t)(i - gj);
            if (selfo < 32u) bits &= ~(1u << selfo);
            mask[(size_t)i * MW + (gj >> 5)] = bits;
        }
    }
}

__global__ void __launch_bounds__(256) k_scan(const uint32_t* __restrict__ mask,
                                              const float4* __restrict__ OP,
                                              float* __restrict__ out) {
    __shared__ uint32_t rem[MW];
    __shared__ uint32_t sidx[64];
    __shared__ uint32_t svL[MW];
    __shared__ uint32_t nsSh;
    __shared__ uint32_t pref[MW];
    int tid = threadIdx.x;
    for (int i = tid; i < MW; i += 256) rem[i] = 0u;
    for (int i = tid; i < K_POST * 4; i += 256) out[i] = 0.0f;
    __syncthreads();
    uint2 mr = make_uint2(0u, 0u);
    if (tid < 64) mr = *(const uint2*)(mask + (size_t)tid * MW);
    for (int c = 0; c < NCHUNK; c++) {
        int base = c * 64;
        int rows = min(64, K_PRE - base);
        if (tid < 64) {
            uint64_t v = ~(((uint64_t)rem[2 * c + 1] << 32) | (uint64_t)rem[2 * c]);
            if (rows < 64) v &= ((1ull << rows) - 1ull);
            uint64_t work = v, surv = 0ull;
            while (work) {
                int k = __ffsll((unsigned long long)work) - 1;
                surv |= 1ull << k;
                uint64_t rowk =
                    ((uint64_t)(uint32_t)__builtin_amdgcn_readlane((int)mr.y, k) << 32)
                  |  (uint64_t)(uint32_t)__builtin_amdgcn_readlane((int)mr.x, k);
                work &= ~rowk;
                work &= ~(1ull << k);
            }
            uint32_t ns = (uint32_t)__popcll(surv);
            if (tid == 0) {
                svL[2 * c]     = (uint32_t)surv;
                svL[2 * c + 1] = (uint32_t)(surv >> 32);
                nsSh = ns;
            }
            if ((surv >> tid) & 1ull) {
                uint32_t pr = __popcll(surv & ((1ull << tid) - 1ull));
                sidx[pr] = (uint32_t)(base + tid);
            }
            if (surv) {
                uint32_t nsPad = (ns + 15u) & ~15u;
                uint32_t first = (uint32_t)base +
                                 (uint32_t)(__ffsll((unsigned long long)surv) - 1);
                if ((uint32_t)tid >= ns && (uint32_t)tid < nsPad) sidx[tid] = first;
            }
            if (c + 1 < NCHUNK)
                mr = *(const uint2*)(mask + (size_t)(base + 64 + tid) * MW + 2 * (c + 1));
        }
        __syncthreads();
        int w = tid - 64;
        if (w >= 0 && w < MW) {
            uint32_t nsPad = (nsSh + 15u) & ~15u;
            uint32_t acc = rem[w];
            for (uint32_t t2 = 0; t2 < nsPad; t2 += 16) {
                uint32_t r[16];
                #pragma unroll
                for (int q = 0; q < 16; q++)
                    r[q] = mask[(size_t)sidx[t2 + q] * MW + w];
                uint32_t o = 0u;
                #pragma unroll
                for (int q = 0; q < 16; q++) o |= r[q];
                acc |= o;
            }
            rem[w] = acc;
        }
        __syncthreads();
    }
    if (tid < MW) {
        uint32_t vv = svL[tid] & ~rem[tid];
        if (tid == MW - 1) vv &= 0xFFFFu;
        rem[tid] = vv;
    }
    __syncthreads();
    if (tid == 0) {
        uint32_t run = 0;
        for (int w2 = 0; w2 < MW; w2++) { pref[w2] = run; run += (uint32_t)__popc(rem[w2]); }
    }
    __syncthreads();
    if (tid < MW) {
        uint32_t b = rem[tid];
        uint32_t r = pref[tid];
        int basebit = tid * 32;
        while (b && r < K_POST) {
            int bit = __ffs(b) - 1;
            b &= b - 1u;
            float4 pp = OP[basebit + bit];
            *(float4*)(out + (size_t)r * 4) = pp;
            r++;
        }
    }
}

extern "C" void kernel_launch(void* const* d_in, const int* in_sizes, int n_in,
                              void* d_out, int out_size, void* d_ws, size_t ws_size,
                              hipStream_t stream) {
    (void)in_sizes; (void)n_in; (void)out_size; (void)ws_size;
    const float* scores = (const float*)d_in[0];
    const float* deltas = (const float*)d_in[1];
    float* out = (float*)d_out;
    char* ws = (char*)d_ws;

    // Primary path: single cooperative dispatch (zeroing done in-kernel).
    void* args[] = { (void*)&scores, (void*)&deltas, (void*)&out, (void*)&ws };
    hipError_t err = hipLaunchCooperativeKernel((const void*)mega, dim3(NBLK), dim3(256),
                                                args, 0, stream);
    if (err == hipSuccess) return;

    // Fallback: previous verified 7-dispatch pipeline (same ws layout).
    uint32_t* hist  = (uint32_t*)(ws + OFF_HIST);
    uint32_t* meta  = (uint32_t*)(ws + OFF_META);
    uint32_t* keys  = (uint32_t*)(ws + OFF_KEYS);
    uint64_t* cand  = (uint64_t*)(ws + OFF_CAND);
    float4*   P     = (float4*)(ws + OFF_P);
    uint64_t* yk    = (uint64_t*)(ws + OFF_YK);
    float4*   OP    = (float4*)(ws + OFF_OP);
    float4*   Q     = (float4*)(ws + OFF_Q);
    float*    Bnd   = (float*)(ws + OFF_BND);
    uint32_t* mask  = (uint32_t*)(ws + OFF_MASK);

    hipMemsetAsync(hist, 0, 4096 * 4 + 320, stream);   // hist + meta
    k_keys_hist<<<N_TOT / 256, 256, 0, stream>>>(scores, deltas, keys, hist);
    k_findbin_compact<<<N_TOT / 256, 256, 0, stream>>>(hist, keys, cand, meta + 1);
    k_rank_props<<<1024, 256, 0, stream>>>(cand, meta, deltas, P, yk);
    k_rank_y2<<<K_PRE / G, 256, 0, stream>>>(yk, P, OP, Q, Bnd);
    k_mask<<<dim3(ROWB, COLB), 256, 0, stream>>>(Q, Bnd, mask);
    k_scan<<<1, 256, 0, stream>>>(mask, OP, out);
}

// Round 2
// 190.794 us; speedup vs baseline: 2.9954x; 2.9954x over previous
//
#include <hip/hip_runtime.h>
#include <cstdint>
#include <cstddef>

#define N_TOT   147456      // 9*128*128
#define K_PRE   6000
#define K_POST  300
#define CAP     32768       // candidate cap (expected ~9.2K)
#define MW      188         // 6016 bits per mask row -> 188 u32 words
#define ROWS_PAD 6016
#define NCHUNK  94
#define CT      128         // k_mask columns per tile
#define ROWB    24
#define COLB    47          // ceil(6000/128)
#define G       16          // candidates ranked per BLOCK

__constant__ float c_sizes[9] = {4.f,8.f,12.f,16.f,24.f,32.f,48.f,64.f,96.f};

// Zero-initialized module globals (load-time .bss). k_scan (last kernel of the
// pipeline) re-zeros them, so every graph replay starts from a clean state
// without a separate memset dispatch (fillBufferAligned was 41 us!).
__device__ uint32_t g_hist[4096];
__device__ uint32_t g_cnt;

// Bit-exact replication of reference box math (anchor + delta, clip).
__device__ __forceinline__ void compute_box(int idx, const float* __restrict__ deltas,
                                            float& px1, float& py1, float& pw, float& ph) {
    int a   = idx >> 14;
    int rem = idx & 16383;
    int h   = rem >> 7;
    int w   = rem & 127;
    float s    = c_sizes[a];
    float half = s * 0.5f;
    const float4 d = *(const float4*)(deltas + (size_t)a * 65536 + (size_t)rem * 4);
    float b0 = (((float)h + 0.5f) - half) + d.x;
    float b1 = (((float)w + 0.5f) - half) + d.y;
    float b2 = s + d.z;
    float b3 = s + d.w;
    b0 = fmaxf(b0, 0.0f); b1 = fmaxf(b1, 0.0f);
    b2 = fmaxf(b2, 0.0f); b3 = fmaxf(b3, 0.0f);
    float x1 = b0, y1 = b1;
    float x2 = b0 + b2, y2 = b1 + b3;
    x1 = fminf(x1, 128.0f); y1 = fminf(y1, 128.0f);
    x2 = fminf(x2, 128.0f); y2 = fminf(y2, 128.0f);
    px1 = x1; py1 = y1; pw = x2 - x1; ph = y2 - y1;
}

__device__ __forceinline__ uint32_t waveReduceSum(uint32_t v) {
    #pragma unroll
    for (int o = 32; o > 0; o >>= 1) v += __shfl_xor(v, o, 64);
    return v;
}

__global__ void k_keys_hist(const float* __restrict__ scores, const float* __restrict__ deltas,
                            uint32_t* __restrict__ keys) {
    __shared__ uint32_t lh[4096];
    for (int i = threadIdx.x; i < 4096; i += 256) lh[i] = 0u;
    __syncthreads();
    int idx = blockIdx.x * 256 + threadIdx.x;
    float px1, py1, pw, ph;
    compute_box(idx, deltas, px1, py1, pw, ph);
    bool keep = (pw >= 3.0f) && (ph >= 3.0f);
    float sc = scores[idx];
    uint32_t key = keep ? __float_as_uint(sc) : 0u;
    keys[idx] = key;
    atomicAdd(&lh[key >> 20], 1u);
    __syncthreads();
    for (int i = threadIdx.x; i < 4096; i += 256) {
        uint32_t v = lh[i];
        if (v) atomicAdd(&g_hist[i], v);
    }
}

// per-block findbin (parallel suffix-scan, no serial walk) + compact slice
__global__ void k_findbin_compact(const uint32_t* __restrict__ keys,
                                  uint64_t* __restrict__ cand) {
    __shared__ uint32_t lh[4096];
    __shared__ uint32_t seg[256];
    __shared__ uint32_t bsh;
    for (int i = threadIdx.x; i < 4096; i += 256) lh[i] = g_hist[i];
    __syncthreads();
    uint32_t s = 0;
    #pragma unroll
    for (int q = 0; q < 16; q++) s += lh[threadIdx.x * 16 + q];
    seg[threadIdx.x] = s;
    __syncthreads();
    // suffix-sum scan (Hillis-Steele, 8 steps): seg[t] = sum of segments >= t
    for (int off = 1; off < 256; off <<= 1) {
        uint32_t v = seg[threadIdx.x];
        if (threadIdx.x + off < 256) v += seg[threadIdx.x + off];
        __syncthreads();
        seg[threadIdx.x] = v;
        __syncthreads();
    }
    uint32_t St  = seg[threadIdx.x];
    uint32_t St1 = (threadIdx.x < 255) ? seg[threadIdx.x + 1] : 0u;
    if (St >= K_PRE && St1 < K_PRE) {     // exactly one thread (when total >= K_PRE)
        uint32_t c2 = St1;
        uint32_t bstar = 0u;
        for (int q = 15; q >= 0; q--) {
            c2 += lh[threadIdx.x * 16 + q];
            if (c2 >= K_PRE) { bstar = (uint32_t)(threadIdx.x * 16 + q); break; }
        }
        bsh = bstar;
    }
    if (threadIdx.x == 0 && seg[0] < K_PRE) bsh = 0u;   // degenerate guard
    __syncthreads();
    uint32_t bstar = bsh;
    int idx = blockIdx.x * 256 + threadIdx.x;
    uint32_t key = keys[idx];
    if ((key >> 20) >= bstar) {
        uint32_t pos = atomicAdd(&g_cnt, 1u);
        if (pos < CAP) cand[pos] = ((uint64_t)key << 32) | (uint32_t)(~(uint32_t)idx);
    }
}

// rank-by-count, block-cooperative: 16 candidates per BLOCK, 256 threads
__global__ void __launch_bounds__(256) k_rank_props(
        const uint64_t* __restrict__ cand,
        const float* __restrict__ deltas,
        float4* __restrict__ P, uint64_t* __restrict__ yk) {
    __shared__ uint32_t part[4][G];
    uint32_t C = g_cnt;
    if (C > CAP) C = CAP;
    uint32_t nGroups = (C + G - 1) / G;
    int tid  = threadIdx.x;
    int wave = tid >> 6, lane = tid & 63;
    for (uint32_t g = blockIdx.x; g < nGroups; g += gridDim.x) {
        uint32_t b = g * G;
        uint64_t m[G];
        uint32_t cnt[G];
        #pragma unroll
        for (int q = 0; q < G; q++) {
            m[q] = (b + q < C) ? cand[b + q] : ~0ull;
            cnt[q] = 0u;
        }
        for (uint32_t j0 = 0; j0 < C; j0 += 1024) {
            uint32_t ja = j0 + tid, jb = ja + 256, jc = ja + 512, jd = ja + 768;
            uint64_t ka = (ja < C) ? cand[ja] : 0ull;   // 0 is never > m[q]
            uint64_t kb = (jb < C) ? cand[jb] : 0ull;
            uint64_t kc = (jc < C) ? cand[jc] : 0ull;
            uint64_t kd = (jd < C) ? cand[jd] : 0ull;
            #pragma unroll
            for (int q = 0; q < G; q++)
                cnt[q] += (uint32_t)(ka > m[q]) + (uint32_t)(kb > m[q])
                        + (uint32_t)(kc > m[q]) + (uint32_t)(kd > m[q]);
        }
        #pragma unroll
        for (int q = 0; q < G; q++) cnt[q] = waveReduceSum(cnt[q]);
        if (lane == 0) {
            #pragma unroll
            for (int q = 0; q < G; q++) part[wave][q] = cnt[q];
        }
        __syncthreads();
        if (tid < G && b + tid < C) {
            uint32_t r = part[0][tid] + part[1][tid] + part[2][tid] + part[3][tid];
            if (r < K_PRE) {
                int idx = (int)(~((uint32_t)cand[b + tid]));
                float px1, py1, pw, ph;
                compute_box(idx, deltas, px1, py1, pw, ph);
                P[r] = make_float4(px1, py1, pw, ph);
                float y2 = py1 + ph;
                yk[r] = ((uint64_t)__float_as_uint(y2) << 32) | (uint32_t)(~r);
            }
        }
        __syncthreads();
    }
}

// stable y2-desc rank, block-cooperative (16 rows/block, 375 blocks); parallel
// epilogue writes OP/Q and the exact div-free boundary.
__global__ void __launch_bounds__(256) k_rank_y2(
        const uint64_t* __restrict__ ykey, const float4* __restrict__ P,
        float4* __restrict__ OP, float4* __restrict__ Q, float* __restrict__ Bnd) {
    __shared__ uint32_t part[4][G];
    int tid  = threadIdx.x;
    int wave = tid >> 6, lane = tid & 63;
    uint32_t b = blockIdx.x * G;      // K_PRE/G = 375 blocks exactly
    uint64_t m[G];
    uint32_t cnt[G];
    #pragma unroll
    for (int q = 0; q < G; q++) {
        m[q] = ykey[b + q];
        cnt[q] = 0u;
    }
    for (uint32_t j0 = 0; j0 < K_PRE; j0 += 1024) {
        uint32_t ja = j0 + tid, jb = ja + 256, jc = ja + 512, jd = ja + 768;
        uint64_t ka = (ja < K_PRE) ? ykey[ja] : 0ull;
        uint64_t kb = (jb < K_PRE) ? ykey[jb] : 0ull;
        uint64_t kc = (jc < K_PRE) ? ykey[jc] : 0ull;
        uint64_t kd = (jd < K_PRE) ? ykey[jd] : 0ull;
        #pragma unroll
        for (int q = 0; q < G; q++)
            cnt[q] += (uint32_t)(ka > m[q]) + (uint32_t)(kb > m[q])
                    + (uint32_t)(kc > m[q]) + (uint32_t)(kd > m[q]);
    }
    #pragma unroll
    for (int q = 0; q < G; q++) cnt[q] = waveReduceSum(cnt[q]);
    if (lane == 0) {
        #pragma unroll
        for (int q = 0; q < G; q++) part[wave][q] = cnt[q];
    }
    __syncthreads();
    if (tid < G) {
        uint32_t r = part[0][tid] + part[1][tid] + part[2][tid] + part[3][tid];
        float4 p = P[b + tid];
        OP[r] = p;
        float x1 = p.x, y1 = p.y;
        float x2 = x1 + p.z, y2 = y1 + p.w;
        float area = fmaxf((x2 - x1) * (y2 - y1), 1e-6f);
        Q[r] = make_float4(x1, y1, x2, y2);
        const double Mc = (double)0.7f - 0x1.0p-25;
        double c = Mc * (double)area;       // exact
        float Bf = (float)c;
        if (!((double)Bf > c)) Bf = __int_as_float(__float_as_int(Bf) + 1);
        Bnd[r] = Bf;
    }
}

// suppression bitmask, tiled: lanes = rows, columns LDS-broadcast; div-free.
__global__ void __launch_bounds__(256) k_mask(const float4* __restrict__ Q,
                                              const float* __restrict__ Bnd,
                                              uint32_t* __restrict__ mask) {
    __shared__ float4 qs[CT];
    __shared__ float  bs[CT];
    int i  = blockIdx.x * 256 + threadIdx.x;     // row
    int c0 = blockIdx.y * CT;                    // first column of tile
    int ncols = min(CT, K_PRE - c0);
    bool rowok = (i < K_PRE);
    float4 qi = rowok ? Q[i] : make_float4(0.f, 0.f, 0.f, 0.f);
    for (int j = threadIdx.x; j < ncols; j += 256) {
        qs[j] = Q[c0 + j];
        bs[j] = Bnd[c0 + j];
    }
    __syncthreads();
    int nw = (ncols + 31) >> 5;
    for (int w = 0; w < nw; w++) {
        uint32_t bits = 0u;
        int jb = w * 32;
        int jn = min(32, ncols - jb);
        #pragma unroll 8
        for (int b = 0; b < jn; b++) {
            int j = jb + b;
            float4 qj = qs[j];
            float iw = fminf(qi.z, qj.z) - fmaxf(qi.x, qj.x) + 1.0f;
            iw = fmaxf(iw, 0.0f);
            float ih = fminf(qi.w, qj.w) - fmaxf(qi.y, qj.y) + 1.0f;
            ih = fmaxf(ih, 0.0f);
            float d = iw * ih;
            bits |= (d >= bs[j]) ? (1u << b) : 0u;
        }
        if (rowok) {
            int gj = c0 + jb;
            uint32_t selfo = (uint32_t)(i - gj);
            if (selfo < 32u) bits &= ~(1u << selfo);     // j == i excluded
            mask[(size_t)i * MW + (gj >> 5)] = bits;
        }
    }
}

// Serial active scan + final validity + emit, single block.
// OR phase now 32-deep (was 16): rounds are latency-bound on scattered L2/L3
// row reads; doubling loads-in-flight ~halves round count.
__global__ void __launch_bounds__(256) k_scan(const uint32_t* __restrict__ mask,
                                              const float4* __restrict__ OP,
                                              float* __restrict__ out) {
    __shared__ uint32_t rem[MW];
    __shared__ uint32_t sidx[64];
    __shared__ uint32_t svL[MW];
    __shared__ uint32_t nsSh;
    __shared__ uint32_t pref[MW];
    int tid = threadIdx.x;
    // restore the module-global invariant for the next replay (hist/cnt were
    // consumed by dispatches 1-3; this kernel is the pipeline's last).
    if (tid < 16) {
        #pragma unroll
        for (int q = 0; q < 16; q++) g_hist[tid * 16 + q] = 0u;
    }
    if (tid == 16) g_cnt = 0u;
    for (int i = tid; i < MW; i += 256) rem[i] = 0u;
    for (int i = tid; i < K_POST * 4; i += 256) out[i] = 0.0f;
    __syncthreads();
    uint2 mr = make_uint2(0u, 0u);
    if (tid < 64) mr = *(const uint2*)(mask + (size_t)tid * MW);   // chunk 0 rows
    for (int c = 0; c < NCHUNK; c++) {
        int base = c * 64;
        int rows = min(64, K_PRE - base);
        if (tid < 64) {
            uint64_t v = ~(((uint64_t)rem[2 * c + 1] << 32) | (uint64_t)rem[2 * c]);
            if (rows < 64) v &= ((1ull << rows) - 1ull);
            uint64_t work = v, surv = 0ull;
            while (work) {                      // leader iteration
                int k = __ffsll((unsigned long long)work) - 1;
                surv |= 1ull << k;
                uint64_t rowk =
                    ((uint64_t)(uint32_t)__builtin_amdgcn_readlane((int)mr.y, k) << 32)
                  |  (uint64_t)(uint32_t)__builtin_amdgcn_readlane((int)mr.x, k);
                work &= ~rowk;
                work &= ~(1ull << k);
            }
            uint32_t ns = (uint32_t)__popcll(surv);
            if (tid == 0) {
                svL[2 * c]     = (uint32_t)surv;
                svL[2 * c + 1] = (uint32_t)(surv >> 32);
                nsSh = ns;
            }
            if ((surv >> tid) & 1ull) {
                uint32_t pr = __popcll(surv & ((1ull << tid) - 1ull));
                sidx[pr] = (uint32_t)(base + tid);
            }
            if (surv) {             // pad sidx to x32 with first survivor (OR-idempotent)
                uint32_t nsPad = (ns + 31u) & ~31u;
                uint32_t first = (uint32_t)base +
                                 (uint32_t)(__ffsll((unsigned long long)surv) - 1);
                if ((uint32_t)tid >= ns && (uint32_t)tid < nsPad) sidx[tid] = first;
            }
            if (c + 1 < NCHUNK)     // prefetch next chunk rows (overlaps OR phase)
                mr = *(const uint2*)(mask + (size_t)(base + 64 + tid) * MW + 2 * (c + 1));
        }
        __syncthreads();
        int w = tid - 64;
        if (w >= 0 && w < MW) {
            uint32_t nsPad = (nsSh + 31u) & ~31u;
            uint32_t acc = rem[w];
            for (uint32_t t2 = 0; t2 < nsPad; t2 += 32) {
                uint32_t r[32];
                #pragma unroll
                for (int q = 0; q < 32; q++)
                    r[q] = mask[(size_t)sidx[t2 + q] * MW + w];
                uint32_t o = 0u;
                #pragma unroll
                for (int q = 0; q < 32; q++) o |= r[q];
                acc |= o;
            }
            rem[w] = acc;
        }
        __syncthreads();
    }
    // final validity + emit first 300 (tail already zeroed above)
    if (tid < MW) {
        uint32_t vv = svL[tid] & ~rem[tid];
        if (tid == MW - 1) vv &= 0xFFFFu;
        rem[tid] = vv;
    }
    __syncthreads();
    if (tid == 0) {
        uint32_t run = 0;
        for (int w2 = 0; w2 < MW; w2++) { pref[w2] = run; run += (uint32_t)__popc(rem[w2]); }
    }
    __syncthreads();
    if (tid < MW) {
        uint32_t b = rem[tid];
        uint32_t r = pref[tid];
        int basebit = tid * 32;
        while (b && r < K_POST) {
            int bit = __ffs(b) - 1;
            b &= b - 1u;
            float4 pp = OP[basebit + bit];
            *(float4*)(out + (size_t)r * 4) = pp;
            r++;
        }
    }
}

extern "C" void kernel_launch(void* const* d_in, const int* in_sizes, int n_in,
                              void* d_out, int out_size, void* d_ws, size_t ws_size,
                              hipStream_t stream) {
    (void)in_sizes; (void)n_in; (void)out_size; (void)ws_size;
    const float* scores = (const float*)d_in[0];
    const float* deltas = (const float*)d_in[1];
    float* out = (float*)d_out;

    char* ws = (char*)d_ws;
    size_t off = 0;
    auto alloc = [&](size_t bytes) -> void* {
        void* p = ws + off;
        off += (bytes + 255) & ~(size_t)255;
        return p;
    };
    uint32_t* keys  = (uint32_t*)alloc((size_t)N_TOT * 4);
    uint64_t* cand  = (uint64_t*)alloc((size_t)CAP * 8);
    float4*   P     = (float4*)alloc((size_t)K_PRE * 16);
    uint64_t* yk    = (uint64_t*)alloc((size_t)K_PRE * 8);
    float4*   OP    = (float4*)alloc((size_t)K_PRE * 16);
    float4*   Q     = (float4*)alloc((size_t)K_PRE * 16);
    float*    Bnd   = (float*)alloc((size_t)K_PRE * 4);
    uint32_t* mask  = (uint32_t*)alloc((size_t)ROWS_PAD * MW * 4);   // ~4.5 MB

    k_keys_hist<<<N_TOT / 256, 256, 0, stream>>>(scores, deltas, keys);
    k_findbin_compact<<<N_TOT / 256, 256, 0, stream>>>(keys, cand);
    k_rank_props<<<1024, 256, 0, stream>>>(cand, deltas, P, yk);
    k_rank_y2<<<K_PRE / G, 256, 0, stream>>>(yk, P, OP, Q, Bnd);
    k_mask<<<dim3(ROWB, COLB), 256, 0, stream>>>(Q, Bnd, mask);
    k_scan<<<1, 256, 0, stream>>>(mask, OP, out);
}

// Round 3
// 156.159 us; speedup vs baseline: 3.6598x; 1.2218x over previous
//
#include <hip/hip_runtime.h>
#include <cstdint>
#include <cstddef>

#define N_TOT   147456      // 9*128*128
#define K_PRE   6000
#define K_POST  300
#define CAP     32768       // candidate cap (expected ~9.2K)
#define MW      188         // 6016 bits per mask row -> 188 u32 words
#define ROWS_PAD 6016
#define CH      128         // k_scan rows per chunk (was 64)
#define NCH     47          // 47*128 = 6016
#define CT      128         // k_mask columns per tile
#define ROWB    24
#define COLB    47          // ceil(6000/128)
#define G       16          // candidates ranked per BLOCK

__constant__ float c_sizes[9] = {4.f,8.f,12.f,16.f,24.f,32.f,48.f,64.f,96.f};

// Zero-initialized module globals (load-time .bss). k_scan (last kernel of the
// pipeline) re-zeros them, so every graph replay starts from a clean state.
__device__ uint32_t g_hist[4096];
__device__ uint32_t g_cnt;

// Bit-exact replication of reference box math (anchor + delta, clip).
__device__ __forceinline__ void compute_box(int idx, const float* __restrict__ deltas,
                                            float& px1, float& py1, float& pw, float& ph) {
    int a   = idx >> 14;
    int rem = idx & 16383;
    int h   = rem >> 7;
    int w   = rem & 127;
    float s    = c_sizes[a];
    float half = s * 0.5f;
    const float4 d = *(const float4*)(deltas + (size_t)a * 65536 + (size_t)rem * 4);
    float b0 = (((float)h + 0.5f) - half) + d.x;
    float b1 = (((float)w + 0.5f) - half) + d.y;
    float b2 = s + d.z;
    float b3 = s + d.w;
    b0 = fmaxf(b0, 0.0f); b1 = fmaxf(b1, 0.0f);
    b2 = fmaxf(b2, 0.0f); b3 = fmaxf(b3, 0.0f);
    float x1 = b0, y1 = b1;
    float x2 = b0 + b2, y2 = b1 + b3;
    x1 = fminf(x1, 128.0f); y1 = fminf(y1, 128.0f);
    x2 = fminf(x2, 128.0f); y2 = fminf(y2, 128.0f);
    px1 = x1; py1 = y1; pw = x2 - x1; ph = y2 - y1;
}

__device__ __forceinline__ uint32_t waveReduceSum(uint32_t v) {
    #pragma unroll
    for (int o = 32; o > 0; o >>= 1) v += __shfl_xor(v, o, 64);
    return v;
}

__global__ void k_keys_hist(const float* __restrict__ scores, const float* __restrict__ deltas,
                            uint32_t* __restrict__ keys) {
    __shared__ uint32_t lh[4096];
    for (int i = threadIdx.x; i < 4096; i += 256) lh[i] = 0u;
    __syncthreads();
    int idx = blockIdx.x * 256 + threadIdx.x;
    float px1, py1, pw, ph;
    compute_box(idx, deltas, px1, py1, pw, ph);
    bool keep = (pw >= 3.0f) && (ph >= 3.0f);
    float sc = scores[idx];
    uint32_t key = keep ? __float_as_uint(sc) : 0u;
    keys[idx] = key;
    atomicAdd(&lh[key >> 20], 1u);
    __syncthreads();
    for (int i = threadIdx.x; i < 4096; i += 256) {
        uint32_t v = lh[i];
        if (v) atomicAdd(&g_hist[i], v);
    }
}

// per-block findbin (parallel suffix-scan) + compact slice.
// Compaction uses a block-aggregated ticket (LDS count -> ONE global atomic
// per block) instead of ~2300 wave-atomics on one address; order in cand[]
// is irrelevant (rank counts strict 64-bit > over the full array; keys unique).
__global__ void k_findbin_compact(const uint32_t* __restrict__ keys,
                                  uint64_t* __restrict__ cand) {
    __shared__ uint32_t lh[4096];
    __shared__ uint32_t seg[256];
    __shared__ uint32_t bsh;
    __shared__ uint32_t lcnt, lbase;
    if (threadIdx.x == 0) lcnt = 0u;
    for (int i = threadIdx.x; i < 4096; i += 256) lh[i] = g_hist[i];
    __syncthreads();
    uint32_t s = 0;
    #pragma unroll
    for (int q = 0; q < 16; q++) s += lh[threadIdx.x * 16 + q];
    seg[threadIdx.x] = s;
    __syncthreads();
    // suffix-sum scan (Hillis-Steele, 8 steps): seg[t] = sum of segments >= t
    for (int off = 1; off < 256; off <<= 1) {
        uint32_t v = seg[threadIdx.x];
        if (threadIdx.x + off < 256) v += seg[threadIdx.x + off];
        __syncthreads();
        seg[threadIdx.x] = v;
        __syncthreads();
    }
    uint32_t St  = seg[threadIdx.x];
    uint32_t St1 = (threadIdx.x < 255) ? seg[threadIdx.x + 1] : 0u;
    if (St >= K_PRE && St1 < K_PRE) {     // exactly one thread (when total >= K_PRE)
        uint32_t c2 = St1;
        uint32_t bstar = 0u;
        for (int q = 15; q >= 0; q--) {
            c2 += lh[threadIdx.x * 16 + q];
            if (c2 >= K_PRE) { bstar = (uint32_t)(threadIdx.x * 16 + q); break; }
        }
        bsh = bstar;
    }
    if (threadIdx.x == 0 && seg[0] < K_PRE) bsh = 0u;   // degenerate guard
    __syncthreads();
    uint32_t bstar = bsh;
    int idx = blockIdx.x * 256 + threadIdx.x;
    uint32_t key = keys[idx];
    bool sel = (key >> 20) >= bstar;
    uint32_t myoff = 0u;
    if (sel) myoff = atomicAdd(&lcnt, 1u);
    __syncthreads();
    if (threadIdx.x == 0) lbase = atomicAdd(&g_cnt, lcnt);
    __syncthreads();
    if (sel) {
        uint32_t pos = lbase + myoff;
        if (pos < CAP) cand[pos] = ((uint64_t)key << 32) | (uint32_t)(~(uint32_t)idx);
    }
}

// rank-by-count, block-cooperative: 16 candidates per BLOCK, 256 threads
__global__ void __launch_bounds__(256) k_rank_props(
        const uint64_t* __restrict__ cand,
        const float* __restrict__ deltas,
        float4* __restrict__ P, uint64_t* __restrict__ yk) {
    __shared__ uint32_t part[4][G];
    uint32_t C = g_cnt;
    if (C > CAP) C = CAP;
    uint32_t nGroups = (C + G - 1) / G;
    int tid  = threadIdx.x;
    int wave = tid >> 6, lane = tid & 63;
    for (uint32_t g = blockIdx.x; g < nGroups; g += gridDim.x) {
        uint32_t b = g * G;
        uint64_t m[G];
        uint32_t cnt[G];
        #pragma unroll
        for (int q = 0; q < G; q++) {
            m[q] = (b + q < C) ? cand[b + q] : ~0ull;
            cnt[q] = 0u;
        }
        for (uint32_t j0 = 0; j0 < C; j0 += 1024) {
            uint32_t ja = j0 + tid, jb = ja + 256, jc = ja + 512, jd = ja + 768;
            uint64_t ka = (ja < C) ? cand[ja] : 0ull;   // 0 is never > m[q]
            uint64_t kb = (jb < C) ? cand[jb] : 0ull;
            uint64_t kc = (jc < C) ? cand[jc] : 0ull;
            uint64_t kd = (jd < C) ? cand[jd] : 0ull;
            #pragma unroll
            for (int q = 0; q < G; q++)
                cnt[q] += (uint32_t)(ka > m[q]) + (uint32_t)(kb > m[q])
                        + (uint32_t)(kc > m[q]) + (uint32_t)(kd > m[q]);
        }
        #pragma unroll
        for (int q = 0; q < G; q++) cnt[q] = waveReduceSum(cnt[q]);
        if (lane == 0) {
            #pragma unroll
            for (int q = 0; q < G; q++) part[wave][q] = cnt[q];
        }
        __syncthreads();
        if (tid < G && b + tid < C) {
            uint32_t r = part[0][tid] + part[1][tid] + part[2][tid] + part[3][tid];
            if (r < K_PRE) {
                int idx = (int)(~((uint32_t)cand[b + tid]));
                float px1, py1, pw, ph;
                compute_box(idx, deltas, px1, py1, pw, ph);
                P[r] = make_float4(px1, py1, pw, ph);
                float y2 = py1 + ph;
                yk[r] = ((uint64_t)__float_as_uint(y2) << 32) | (uint32_t)(~r);
            }
        }
        __syncthreads();
    }
}

// stable y2-desc rank, block-cooperative (16 rows/block, 375 blocks); parallel
// epilogue writes OP/Q and the exact div-free boundary.
__global__ void __launch_bounds__(256) k_rank_y2(
        const uint64_t* __restrict__ ykey, const float4* __restrict__ P,
        float4* __restrict__ OP, float4* __restrict__ Q, float* __restrict__ Bnd) {
    __shared__ uint32_t part[4][G];
    int tid  = threadIdx.x;
    int wave = tid >> 6, lane = tid & 63;
    uint32_t b = blockIdx.x * G;      // K_PRE/G = 375 blocks exactly
    uint64_t m[G];
    uint32_t cnt[G];
    #pragma unroll
    for (int q = 0; q < G; q++) {
        m[q] = ykey[b + q];
        cnt[q] = 0u;
    }
    for (uint32_t j0 = 0; j0 < K_PRE; j0 += 1024) {
        uint32_t ja = j0 + tid, jb = ja + 256, jc = ja + 512, jd = ja + 768;
        uint64_t ka = (ja < K_PRE) ? ykey[ja] : 0ull;
        uint64_t kb = (jb < K_PRE) ? ykey[jb] : 0ull;
        uint64_t kc = (jc < K_PRE) ? ykey[jc] : 0ull;
        uint64_t kd = (jd < K_PRE) ? ykey[jd] : 0ull;
        #pragma unroll
        for (int q = 0; q < G; q++)
            cnt[q] += (uint32_t)(ka > m[q]) + (uint32_t)(kb > m[q])
                    + (uint32_t)(kc > m[q]) + (uint32_t)(kd > m[q]);
    }
    #pragma unroll
    for (int q = 0; q < G; q++) cnt[q] = waveReduceSum(cnt[q]);
    if (lane == 0) {
        #pragma unroll
        for (int q = 0; q < G; q++) part[wave][q] = cnt[q];
    }
    __syncthreads();
    if (tid < G) {
        uint32_t r = part[0][tid] + part[1][tid] + part[2][tid] + part[3][tid];
        float4 p = P[b + tid];
        OP[r] = p;
        float x1 = p.x, y1 = p.y;
        float x2 = x1 + p.z, y2 = y1 + p.w;
        float area = fmaxf((x2 - x1) * (y2 - y1), 1e-6f);
        Q[r] = make_float4(x1, y1, x2, y2);
        const double Mc = (double)0.7f - 0x1.0p-25;
        double c = Mc * (double)area;       // exact
        float Bf = (float)c;
        if (!((double)Bf > c)) Bf = __int_as_float(__float_as_int(Bf) + 1);
        Bnd[r] = Bf;
    }
}

// suppression bitmask, tiled: lanes = rows, columns LDS-broadcast; div-free.
__global__ void __launch_bounds__(256) k_mask(const float4* __restrict__ Q,
                                              const float* __restrict__ Bnd,
                                              uint32_t* __restrict__ mask) {
    __shared__ float4 qs[CT];
    __shared__ float  bs[CT];
    int i  = blockIdx.x * 256 + threadIdx.x;     // row
    int c0 = blockIdx.y * CT;                    // first column of tile
    int ncols = min(CT, K_PRE - c0);
    bool rowok = (i < K_PRE);
    float4 qi = rowok ? Q[i] : make_float4(0.f, 0.f, 0.f, 0.f);
    for (int j = threadIdx.x; j < ncols; j += 256) {
        qs[j] = Q[c0 + j];
        bs[j] = Bnd[c0 + j];
    }
    __syncthreads();
    int nw = (ncols + 31) >> 5;
    for (int w = 0; w < nw; w++) {
        uint32_t bits = 0u;
        int jb = w * 32;
        int jn = min(32, ncols - jb);
        #pragma unroll 8
        for (int b = 0; b < jn; b++) {
            int j = jb + b;
            float4 qj = qs[j];
            float iw = fminf(qi.z, qj.z) - fmaxf(qi.x, qj.x) + 1.0f;
            iw = fmaxf(iw, 0.0f);
            float ih = fminf(qi.w, qj.w) - fmaxf(qi.y, qj.y) + 1.0f;
            ih = fmaxf(ih, 0.0f);
            float d = iw * ih;
            bits |= (d >= bs[j]) ? (1u << b) : 0u;
        }
        if (rowok) {
            int gj = c0 + jb;
            uint32_t selfo = (uint32_t)(i - gj);
            if (selfo < 32u) bits &= ~(1u << selfo);     // j == i excluded
            mask[(size_t)i * MW + (gj >> 5)] = bits;
        }
    }
}

// Serial active scan, 128-row chunks (47 chunks, was 94x64). Total leader
// iterations == total survivors (~300) regardless of chunk size; the ~500cyc
// scattered-load round trip per chunk is what costs, so halving chunk count
// ~halves the kernel. Lane l owns rows base+l (mrA) and base+64+l (mrB);
// intra-chunk columns = 4 words. Backward kills via final svL & ~rem as before.
__global__ void __launch_bounds__(256) k_scan(const uint32_t* __restrict__ mask,
                                              const float4* __restrict__ OP,
                                              float* __restrict__ out) {
    __shared__ uint32_t rem[MW];
    __shared__ uint32_t sidx[CH];
    __shared__ uint32_t svL[MW];
    __shared__ uint32_t nsSh;
    __shared__ uint32_t pref[MW];
    int tid = threadIdx.x;
    // restore module-global invariant for the next replay
    if (tid < 16) {
        #pragma unroll
        for (int q = 0; q < 16; q++) g_hist[tid * 16 + q] = 0u;
    }
    if (tid == 16) g_cnt = 0u;
    for (int i = tid; i < MW; i += 256) rem[i] = 0u;
    for (int i = tid; i < K_POST * 4; i += 256) out[i] = 0.0f;
    __syncthreads();
    uint4 mrA = make_uint4(0u,0u,0u,0u), mrB = make_uint4(0u,0u,0u,0u);
    if (tid < 64) {
        mrA = *(const uint4*)(mask + (size_t)tid * MW);          // rows 0..63, words 0..3
        mrB = *(const uint4*)(mask + (size_t)(64 + tid) * MW);   // rows 64..127
    }
    for (int c = 0; c < NCH; c++) {
        int base = c * CH;
        int rows = min(CH, K_PRE - base);      // 128 except last (112)
        if (tid < 64) {
            uint32_t r0 = rem[4*c], r1 = rem[4*c+1], r2 = rem[4*c+2], r3 = rem[4*c+3];
            uint64_t vLo = ~(((uint64_t)r1 << 32) | (uint64_t)r0);
            uint64_t vHi = ~(((uint64_t)r3 << 32) | (uint64_t)r2);
            if (rows < CH) {
                if (rows <= 64) {
                    vLo &= (rows == 64) ? ~0ull : ((1ull << rows) - 1ull);
                    vHi = 0ull;
                } else {
                    vHi &= ((1ull << (rows - 64)) - 1ull);
                }
            }
            uint64_t workLo = vLo, workHi = vHi;
            uint64_t survLo = 0ull, survHi = 0ull;
            while (workLo | workHi) {           // leader iteration (one per survivor)
                int slot, k;
                if (workLo) { k = __ffsll((unsigned long long)workLo) - 1; slot = 0; }
                else        { k = __ffsll((unsigned long long)workHi) - 1; slot = 1; }
                uint4 sel = slot ? mrB : mrA;   // slot is wave-uniform
                uint64_t rLo =
                    ((uint64_t)(uint32_t)__builtin_amdgcn_readlane((int)sel.y, k) << 32)
                  |  (uint64_t)(uint32_t)__builtin_amdgcn_readlane((int)sel.x, k);
                uint64_t rHi =
                    ((uint64_t)(uint32_t)__builtin_amdgcn_readlane((int)sel.w, k) << 32)
                  |  (uint64_t)(uint32_t)__builtin_amdgcn_readlane((int)sel.z, k);
                if (slot == 0) { survLo |= 1ull << k; workLo &= ~(1ull << k); }
                else           { survHi |= 1ull << k; workHi &= ~(1ull << k); }
                workLo &= ~rLo;                 // forward kills, both halves
                workHi &= ~rHi;
            }
            uint32_t nsLo = (uint32_t)__popcll(survLo);
            uint32_t ns   = nsLo + (uint32_t)__popcll(survHi);
            if (tid == 0) {
                svL[4*c]   = (uint32_t)survLo;
                svL[4*c+1] = (uint32_t)(survLo >> 32);
                svL[4*c+2] = (uint32_t)survHi;
                svL[4*c+3] = (uint32_t)(survHi >> 32);
                nsSh = ns;
            }
            // survivor index compaction (lane-parallel, both halves)
            if ((survLo >> tid) & 1ull)
                sidx[__popcll(survLo & ((1ull << tid) - 1ull))] = (uint32_t)(base + tid);
            if ((survHi >> tid) & 1ull)
                sidx[nsLo + __popcll(survHi & ((1ull << tid) - 1ull))] = (uint32_t)(base + 64 + tid);
            if (ns) {                           // pad to x32 with first survivor (OR-idempotent)
                uint32_t nsPad = (ns + 31u) & ~31u;         // <= 128
                uint64_t f = survLo ? survLo : survHi;
                uint32_t first = (uint32_t)base + (survLo ? 0u : 64u) +
                                 (uint32_t)(__ffsll((unsigned long long)f) - 1);
                if ((uint32_t)tid >= ns && (uint32_t)tid < nsPad) sidx[tid] = first;
                uint32_t hi = (uint32_t)tid + 64u;
                if (hi >= ns && hi < nsPad) sidx[hi] = first;
            }
            if (c + 1 < NCH) {                  // prefetch next chunk rows (overlaps OR phase)
                mrA = *(const uint4*)(mask + (size_t)(base + 128 + tid) * MW + 4*(c+1));
                mrB = *(const uint4*)(mask + (size_t)(base + 192 + tid) * MW + 4*(c+1));
            }
        }
        __syncthreads();
        int w = tid - 64;
        if (w >= 0 && w < MW) {
            uint32_t nsPad = (nsSh + 31u) & ~31u;
            uint32_t acc = rem[w];
            for (uint32_t t2 = 0; t2 < nsPad; t2 += 32) {
                uint32_t r[32];
                #pragma unroll
                for (int q = 0; q < 32; q++)
                    r[q] = mask[(size_t)sidx[t2 + q] * MW + w];
                uint32_t o = 0u;
                #pragma unroll
                for (int q = 0; q < 32; q++) o |= r[q];
                acc |= o;
            }
            rem[w] = acc;
        }
        __syncthreads();
    }
    // final validity + emit first 300 (tail already zeroed above)
    if (tid < MW) {
        uint32_t vv = svL[tid] & ~rem[tid];
        if (tid == MW - 1) vv &= 0xFFFFu;
        rem[tid] = vv;
    }
    __syncthreads();
    if (tid == 0) {
        uint32_t run = 0;
        for (int w2 = 0; w2 < MW; w2++) { pref[w2] = run; run += (uint32_t)__popc(rem[w2]); }
    }
    __syncthreads();
    if (tid < MW) {
        uint32_t b = rem[tid];
        uint32_t r = pref[tid];
        int basebit = tid * 32;
        while (b && r < K_POST) {
            int bit = __ffs(b) - 1;
            b &= b - 1u;
            float4 pp = OP[basebit + bit];
            *(float4*)(out + (size_t)r * 4) = pp;
            r++;
        }
    }
}

extern "C" void kernel_launch(void* const* d_in, const int* in_sizes, int n_in,
                              void* d_out, int out_size, void* d_ws, size_t ws_size,
                              hipStream_t stream) {
    (void)in_sizes; (void)n_in; (void)out_size; (void)ws_size;
    const float* scores = (const float*)d_in[0];
    const float* deltas = (const float*)d_in[1];
    float* out = (float*)d_out;

    char* ws = (char*)d_ws;
    size_t off = 0;
    auto alloc = [&](size_t bytes) -> void* {
        void* p = ws + off;
        off += (bytes + 255) & ~(size_t)255;
        return p;
    };
    uint32_t* keys  = (uint32_t*)alloc((size_t)N_TOT * 4);
    uint64_t* cand  = (uint64_t*)alloc((size_t)CAP * 8);
    float4*   P     = (float4*)alloc((size_t)K_PRE * 16);
    uint64_t* yk    = (uint64_t*)alloc((size_t)K_PRE * 8);
    float4*   OP    = (float4*)alloc((size_t)K_PRE * 16);
    float4*   Q     = (float4*)alloc((size_t)K_PRE * 16);
    float*    Bnd   = (float*)alloc((size_t)K_PRE * 4);
    uint32_t* mask  = (uint32_t*)alloc((size_t)ROWS_PAD * MW * 4);   // ~4.5 MB

    k_keys_hist<<<N_TOT / 256, 256, 0, stream>>>(scores, deltas, keys);
    k_findbin_compact<<<N_TOT / 256, 256, 0, stream>>>(keys, cand);
    k_rank_props<<<1024, 256, 0, stream>>>(cand, deltas, P, yk);
    k_rank_y2<<<K_PRE / G, 256, 0, stream>>>(yk, P, OP, Q, Bnd);
    k_mask<<<dim3(ROWB, COLB), 256, 0, stream>>>(Q, Bnd, mask);
    k_scan<<<1, 256, 0, stream>>>(mask, OP, out);
}

// Round 5
// 143.271 us; speedup vs baseline: 3.9891x; 1.0900x over previous
//
#include <hip/hip_runtime.h>
#include <cstdint>
#include <cstddef>

#define N_TOT   147456      // 9*128*128
#define K_PRE   6000
#define K_POST  300
#define CAP     32768       // candidate cap (expected ~9.2K)
#define MW      188         // 6016 bits per mask row -> 188 u32 words
#define ROWS_PAD 6144       // 24*256 (k_scan prefetch range)
#define CH      256         // k_scan rows per chunk
#define NCH     24          // 24*256 = 6144
#define CT      128         // k_mask columns per tile
#define ROWB    24
#define COLB    47          // ceil(6000/128)
#define G       16          // candidates ranked per BLOCK

__constant__ float c_sizes[9] = {4.f,8.f,12.f,16.f,24.f,32.f,48.f,64.f,96.f};

// Zero-initialized module globals (load-time .bss). k_scan (last kernel of the
// pipeline) re-zeros them, so every graph replay starts from a clean state.
__device__ uint32_t g_hist[4096];
__device__ uint32_t g_cnt;

// Bit-exact replication of reference box math (anchor + delta, clip).
__device__ __forceinline__ void compute_box(int idx, const float* __restrict__ deltas,
                                            float& px1, float& py1, float& pw, float& ph) {
    int a   = idx >> 14;
    int rem = idx & 16383;
    int h   = rem >> 7;
    int w   = rem & 127;
    float s    = c_sizes[a];
    float half = s * 0.5f;
    const float4 d = *(const float4*)(deltas + (size_t)a * 65536 + (size_t)rem * 4);
    float b0 = (((float)h + 0.5f) - half) + d.x;
    float b1 = (((float)w + 0.5f) - half) + d.y;
    float b2 = s + d.z;
    float b3 = s + d.w;
    b0 = fmaxf(b0, 0.0f); b1 = fmaxf(b1, 0.0f);
    b2 = fmaxf(b2, 0.0f); b3 = fmaxf(b3, 0.0f);
    float x1 = b0, y1 = b1;
    float x2 = b0 + b2, y2 = b1 + b3;
    x1 = fminf(x1, 128.0f); y1 = fminf(y1, 128.0f);
    x2 = fminf(x2, 128.0f); y2 = fminf(y2, 128.0f);
    px1 = x1; py1 = y1; pw = x2 - x1; ph = y2 - y1;
}

__device__ __forceinline__ uint32_t waveReduceSum(uint32_t v) {
    #pragma unroll
    for (int o = 32; o > 0; o >>= 1) v += __shfl_xor(v, o, 64);
    return v;
}

// 4 anchors per thread (144 blocks): float4 score loads, uint4 key store,
// 4x fewer per-block global-hist atomic flushes.
__global__ void k_keys_hist(const float* __restrict__ scores, const float* __restrict__ deltas,
                            uint32_t* __restrict__ keys) {
    __shared__ uint32_t lh[4096];
    for (int i = threadIdx.x; i < 4096; i += 256) lh[i] = 0u;
    __syncthreads();
    int t4 = (blockIdx.x * 256 + threadIdx.x) * 4;
    float4 sc4 = *(const float4*)(scores + t4);
    uint32_t k4[4];
    #pragma unroll
    for (int e = 0; e < 4; e++) {
        int idx = t4 + e;
        float px1, py1, pw, ph;
        compute_box(idx, deltas, px1, py1, pw, ph);
        bool keep = (pw >= 3.0f) && (ph >= 3.0f);
        float sc = (&sc4.x)[e];
        uint32_t key = keep ? __float_as_uint(sc) : 0u;
        k4[e] = key;
        atomicAdd(&lh[key >> 20], 1u);
    }
    *(uint4*)(keys + t4) = make_uint4(k4[0], k4[1], k4[2], k4[3]);
    __syncthreads();
    for (int i = threadIdx.x; i < 4096; i += 256) {
        uint32_t v = lh[i];
        if (v) atomicAdd(&g_hist[i], v);
    }
}

// per-block findbin (parallel suffix-scan) + compact slice, 4 keys/thread
// (144 blocks -> 4x less hist traffic). Block-aggregated ticket: one global
// atomic per block; order in cand[] irrelevant (rank counts strict 64-bit >).
__global__ void k_findbin_compact(const uint32_t* __restrict__ keys,
                                  uint64_t* __restrict__ cand) {
    __shared__ uint32_t lh[4096];
    __shared__ uint32_t seg[256];
    __shared__ uint32_t bsh;
    __shared__ uint32_t lcnt, lbase;
    if (threadIdx.x == 0) lcnt = 0u;
    for (int i = threadIdx.x; i < 4096; i += 256) lh[i] = g_hist[i];
    __syncthreads();
    uint32_t s = 0;
    #pragma unroll
    for (int q = 0; q < 16; q++) s += lh[threadIdx.x * 16 + q];
    seg[threadIdx.x] = s;
    __syncthreads();
    // suffix-sum scan (Hillis-Steele, 8 steps): seg[t] = sum of segments >= t
    for (int off = 1; off < 256; off <<= 1) {
        uint32_t v = seg[threadIdx.x];
        if (threadIdx.x + off < 256) v += seg[threadIdx.x + off];
        __syncthreads();
        seg[threadIdx.x] = v;
        __syncthreads();
    }
    uint32_t St  = seg[threadIdx.x];
    uint32_t St1 = (threadIdx.x < 255) ? seg[threadIdx.x + 1] : 0u;
    if (St >= K_PRE && St1 < K_PRE) {     // exactly one thread (when total >= K_PRE)
        uint32_t c2 = St1;
        uint32_t bstar = 0u;
        for (int q = 15; q >= 0; q--) {
            c2 += lh[threadIdx.x * 16 + q];
            if (c2 >= K_PRE) { bstar = (uint32_t)(threadIdx.x * 16 + q); break; }
        }
        bsh = bstar;
    }
    if (threadIdx.x == 0 && seg[0] < K_PRE) bsh = 0u;   // degenerate guard
    __syncthreads();
    uint32_t bstar = bsh;
    int t4 = (blockIdx.x * 256 + threadIdx.x) * 4;
    uint4 kk = *(const uint4*)(keys + t4);
    bool s0 = (kk.x >> 20) >= bstar;
    bool s1 = (kk.y >> 20) >= bstar;
    bool s2 = (kk.z >> 20) >= bstar;
    bool s3 = (kk.w >> 20) >= bstar;
    uint32_t nsel = (uint32_t)s0 + s1 + s2 + s3;
    uint32_t myoff = 0u;
    if (nsel) myoff = atomicAdd(&lcnt, nsel);
    __syncthreads();
    if (threadIdx.x == 0) lbase = atomicAdd(&g_cnt, lcnt);
    __syncthreads();
    uint32_t pos = lbase + myoff;
    if (s0) { if (pos < CAP) cand[pos] = ((uint64_t)kk.x << 32) | (uint32_t)(~(uint32_t)(t4 + 0)); pos++; }
    if (s1) { if (pos < CAP) cand[pos] = ((uint64_t)kk.y << 32) | (uint32_t)(~(uint32_t)(t4 + 1)); pos++; }
    if (s2) { if (pos < CAP) cand[pos] = ((uint64_t)kk.z << 32) | (uint32_t)(~(uint32_t)(t4 + 2)); pos++; }
    if (s3) { if (pos < CAP) cand[pos] = ((uint64_t)kk.w << 32) | (uint32_t)(~(uint32_t)(t4 + 3)); }
}

// rank-by-count, block-cooperative: 16 candidates per BLOCK, 256 threads
__global__ void __launch_bounds__(256) k_rank_props(
        const uint64_t* __restrict__ cand,
        const float* __restrict__ deltas,
        float4* __restrict__ P, uint64_t* __restrict__ yk) {
    __shared__ uint32_t part[4][G];
    uint32_t C = g_cnt;
    if (C > CAP) C = CAP;
    uint32_t nGroups = (C + G - 1) / G;
    int tid  = threadIdx.x;
    int wave = tid >> 6, lane = tid & 63;
    for (uint32_t g = blockIdx.x; g < nGroups; g += gridDim.x) {
        uint32_t b = g * G;
        uint64_t m[G];
        uint32_t cnt[G];
        #pragma unroll
        for (int q = 0; q < G; q++) {
            m[q] = (b + q < C) ? cand[b + q] : ~0ull;
            cnt[q] = 0u;
        }
        for (uint32_t j0 = 0; j0 < C; j0 += 1024) {
            uint32_t ja = j0 + tid, jb = ja + 256, jc = ja + 512, jd = ja + 768;
            uint64_t ka = (ja < C) ? cand[ja] : 0ull;   // 0 is never > m[q]
            uint64_t kb = (jb < C) ? cand[jb] : 0ull;
            uint64_t kc = (jc < C) ? cand[jc] : 0ull;
            uint64_t kd = (jd < C) ? cand[jd] : 0ull;
            #pragma unroll
            for (int q = 0; q < G; q++)
                cnt[q] += (uint32_t)(ka > m[q]) + (uint32_t)(kb > m[q])
                        + (uint32_t)(kc > m[q]) + (uint32_t)(kd > m[q]);
        }
        #pragma unroll
        for (int q = 0; q < G; q++) cnt[q] = waveReduceSum(cnt[q]);
        if (lane == 0) {
            #pragma unroll
            for (int q = 0; q < G; q++) part[wave][q] = cnt[q];
        }
        __syncthreads();
        if (tid < G && b + tid < C) {
            uint32_t r = part[0][tid] + part[1][tid] + part[2][tid] + part[3][tid];
            if (r < K_PRE) {
                int idx = (int)(~((uint32_t)cand[b + tid]));
                float px1, py1, pw, ph;
                compute_box(idx, deltas, px1, py1, pw, ph);
                P[r] = make_float4(px1, py1, pw, ph);
                float y2 = py1 + ph;
                yk[r] = ((uint64_t)__float_as_uint(y2) << 32) | (uint32_t)(~r);
            }
        }
        __syncthreads();
    }
}

// stable y2-desc rank, block-cooperative (16 rows/block, 375 blocks); parallel
// epilogue writes OP/Q and the exact div-free boundary.
__global__ void __launch_bounds__(256) k_rank_y2(
        const uint64_t* __restrict__ ykey, const float4* __restrict__ P,
        float4* __restrict__ OP, float4* __restrict__ Q, float* __restrict__ Bnd) {
    __shared__ uint32_t part[4][G];
    int tid  = threadIdx.x;
    int wave = tid >> 6, lane = tid & 63;
    uint32_t b = blockIdx.x * G;      // K_PRE/G = 375 blocks exactly
    uint64_t m[G];
    uint32_t cnt[G];
    #pragma unroll
    for (int q = 0; q < G; q++) {
        m[q] = ykey[b + q];
        cnt[q] = 0u;
    }
    for (uint32_t j0 = 0; j0 < K_PRE; j0 += 1024) {
        uint32_t ja = j0 + tid, jb = ja + 256, jc = ja + 512, jd = ja + 768;
        uint64_t ka = (ja < K_PRE) ? ykey[ja] : 0ull;
        uint64_t kb = (jb < K_PRE) ? ykey[jb] : 0ull;
        uint64_t kc = (jc < K_PRE) ? ykey[jc] : 0ull;
        uint64_t kd = (jd < K_PRE) ? ykey[jd] : 0ull;
        #pragma unroll
        for (int q = 0; q < G; q++)
            cnt[q] += (uint32_t)(ka > m[q]) + (uint32_t)(kb > m[q])
                    + (uint32_t)(kc > m[q]) + (uint32_t)(kd > m[q]);
    }
    #pragma unroll
    for (int q = 0; q < G; q++) cnt[q] = waveReduceSum(cnt[q]);
    if (lane == 0) {
        #pragma unroll
        for (int q = 0; q < G; q++) part[wave][q] = cnt[q];
    }
    __syncthreads();
    if (tid < G) {
        uint32_t r = part[0][tid] + part[1][tid] + part[2][tid] + part[3][tid];
        float4 p = P[b + tid];
        OP[r] = p;
        float x1 = p.x, y1 = p.y;
        float x2 = x1 + p.z, y2 = y1 + p.w;
        float area = fmaxf((x2 - x1) * (y2 - y1), 1e-6f);
        Q[r] = make_float4(x1, y1, x2, y2);
        const double Mc = (double)0.7f - 0x1.0p-25;
        double c = Mc * (double)area;       // exact
        float Bf = (float)c;
        if (!((double)Bf > c)) Bf = __int_as_float(__float_as_int(Bf) + 1);
        Bnd[r] = Bf;
    }
}

// suppression bitmask, tiled: lanes = rows, columns LDS-broadcast; div-free.
__global__ void __launch_bounds__(256) k_mask(const float4* __restrict__ Q,
                                              const float* __restrict__ Bnd,
                                              uint32_t* __restrict__ mask) {
    __shared__ float4 qs[CT];
    __shared__ float  bs[CT];
    int i  = blockIdx.x * 256 + threadIdx.x;     // row
    int c0 = blockIdx.y * CT;                    // first column of tile
    int ncols = min(CT, K_PRE - c0);
    bool rowok = (i < K_PRE);
    float4 qi = rowok ? Q[i] : make_float4(0.f, 0.f, 0.f, 0.f);
    for (int j = threadIdx.x; j < ncols; j += 256) {
        qs[j] = Q[c0 + j];
        bs[j] = Bnd[c0 + j];
    }
    __syncthreads();
    int nw = (ncols + 31) >> 5;
    for (int w = 0; w < nw; w++) {
        uint32_t bits = 0u;
        int jb = w * 32;
        int jn = min(32, ncols - jb);
        #pragma unroll 8
        for (int b = 0; b < jn; b++) {
            int j = jb + b;
            float4 qj = qs[j];
            float iw = fminf(qi.z, qj.z) - fmaxf(qi.x, qj.x) + 1.0f;
            iw = fmaxf(iw, 0.0f);
            float ih = fminf(qi.w, qj.w) - fmaxf(qi.y, qj.y) + 1.0f;
            ih = fmaxf(ih, 0.0f);
            float d = iw * ih;
            bits |= (d >= bs[j]) ? (1u << b) : 0u;
        }
        if (rowok) {
            int gj = c0 + jb;
            uint32_t selfo = (uint32_t)(i - gj);
            if (selfo < 32u) bits &= ~(1u << selfo);     // j == i excluded
            mask[(size_t)i * MW + (gj >> 5)] = bits;
        }
    }
}

// Serial active scan, 256-row chunks (24 chunks). Critical path per chunk is
// one scattered mask-row round trip + 2 barriers; total leader iterations ==
// total survivors (~300) regardless of chunk size. Lane l holds rows
// base+64s+l (s=0..3) as 2 uint4 each (8 words = 256-bit intra-chunk segment).
// Backward kills via final svL & ~rem as before.
__global__ void __launch_bounds__(256) k_scan(const uint32_t* __restrict__ mask,
                                              const float4* __restrict__ OP,
                                              float* __restrict__ out) {
    __shared__ uint32_t rem[192];        // 24*8; words >= MW unused in epilogue
    __shared__ uint32_t sidx[CH];
    __shared__ uint32_t svL[192];
    __shared__ uint32_t nsSh;
    __shared__ uint32_t pref[MW];
    int tid = threadIdx.x;
    // restore module-global invariant for the next replay
    if (tid < 16) {
        #pragma unroll
        for (int q = 0; q < 16; q++) g_hist[tid * 16 + q] = 0u;
    }
    if (tid == 16) g_cnt = 0u;
    if (tid < 192) { rem[tid] = 0u; svL[tid] = 0u; }
    for (int i = tid; i < K_POST * 4; i += 256) out[i] = 0.0f;
    __syncthreads();
    uint4 s00 = make_uint4(0,0,0,0), s01 = s00, s10 = s00, s11 = s00;
    uint4 s20 = s00, s21 = s00, s30 = s00, s31 = s00;
    if (tid < 64) {                      // chunk-0 row segments
        const uint32_t* p0 = mask + (size_t)(tid) * MW;
        s00 = *(const uint4*)p0;       s01 = *(const uint4*)(p0 + 4);
        const uint32_t* p1 = mask + (size_t)(64 + tid) * MW;
        s10 = *(const uint4*)p1;       s11 = *(const uint4*)(p1 + 4);
        const uint32_t* p2 = mask + (size_t)(128 + tid) * MW;
        s20 = *(const uint4*)p2;       s21 = *(const uint4*)(p2 + 4);
        const uint32_t* p3 = mask + (size_t)(192 + tid) * MW;
        s30 = *(const uint4*)p3;       s31 = *(const uint4*)(p3 + 4);
    }
    for (int c = 0; c < NCH; c++) {
        int base = c * CH;
        if (tid < 64) {
            uint64_t w0 = ~(((uint64_t)rem[8*c+1] << 32) | (uint64_t)rem[8*c+0]);
            uint64_t w1 = ~(((uint64_t)rem[8*c+3] << 32) | (uint64_t)rem[8*c+2]);
            uint64_t w2 = ~(((uint64_t)rem[8*c+5] << 32) | (uint64_t)rem[8*c+4]);
            uint64_t w3 = ~(((uint64_t)rem[8*c+7] << 32) | (uint64_t)rem[8*c+6]);
            int rows = K_PRE - base;                    // >=256 except last (112)
            if (rows < CH) {
                auto msk = [](int v) -> uint64_t {
                    return v <= 0 ? 0ull : (v >= 64 ? ~0ull : ((1ull << v) - 1ull));
                };
                w0 &= msk(rows); w1 &= msk(rows - 64);
                w2 &= msk(rows - 128); w3 &= msk(rows - 192);
            }
            uint64_t sv0 = 0ull, sv1 = 0ull, sv2 = 0ull, sv3 = 0ull;
            while (w0 | w1 | w2 | w3) {                 // one iter per survivor
                int k;
                uint32_t a0, a1, a2, a3, a4, a5, a6, a7;
                if (w0) {
                    k = __ffsll((unsigned long long)w0) - 1;
                    sv0 |= 1ull << k; w0 &= ~(1ull << k);
                    a0 = (uint32_t)__builtin_amdgcn_readlane((int)s00.x, k);
                    a1 = (uint32_t)__builtin_amdgcn_readlane((int)s00.y, k);
                    a2 = (uint32_t)__builtin_amdgcn_readlane((int)s00.z, k);
                    a3 = (uint32_t)__builtin_amdgcn_readlane((int)s00.w, k);
                    a4 = (uint32_t)__builtin_amdgcn_readlane((int)s01.x, k);
                    a5 = (uint32_t)__builtin_amdgcn_readlane((int)s01.y, k);
                    a6 = (uint32_t)__builtin_amdgcn_readlane((int)s01.z, k);
                    a7 = (uint32_t)__builtin_amdgcn_readlane((int)s01.w, k);
                } else if (w1) {
                    k = __ffsll((unsigned long long)w1) - 1;
                    sv1 |= 1ull << k; w1 &= ~(1ull << k);
                    a0 = (uint32_t)__builtin_amdgcn_readlane((int)s10.x, k);
                    a1 = (uint32_t)__builtin_amdgcn_readlane((int)s10.y, k);
                    a2 = (uint32_t)__builtin_amdgcn_readlane((int)s10.z, k);
                    a3 = (uint32_t)__builtin_amdgcn_readlane((int)s10.w, k);
                    a4 = (uint32_t)__builtin_amdgcn_readlane((int)s11.x, k);
                    a5 = (uint32_t)__builtin_amdgcn_readlane((int)s11.y, k);
                    a6 = (uint32_t)__builtin_amdgcn_readlane((int)s11.z, k);
                    a7 = (uint32_t)__builtin_amdgcn_readlane((int)s11.w, k);
                } else if (w2) {
                    k = __ffsll((unsigned long long)w2) - 1;
                    sv2 |= 1ull << k; w2 &= ~(1ull << k);
                    a0 = (uint32_t)__builtin_amdgcn_readlane((int)s20.x, k);
                    a1 = (uint32_t)__builtin_amdgcn_readlane((int)s20.y, k);
                    a2 = (uint32_t)__builtin_amdgcn_readlane((int)s20.z, k);
                    a3 = (uint32_t)__builtin_amdgcn_readlane((int)s20.w, k);
                    a4 = (uint32_t)__builtin_amdgcn_readlane((int)s21.x, k);
                    a5 = (uint32_t)__builtin_amdgcn_readlane((int)s21.y, k);
                    a6 = (uint32_t)__builtin_amdgcn_readlane((int)s21.z, k);
                    a7 = (uint32_t)__builtin_amdgcn_readlane((int)s21.w, k);
                } else {
                    k = __ffsll((unsigned long long)w3) - 1;
                    sv3 |= 1ull << k; w3 &= ~(1ull << k);
                    a0 = (uint32_t)__builtin_amdgcn_readlane((int)s30.x, k);
                    a1 = (uint32_t)__builtin_amdgcn_readlane((int)s30.y, k);
                    a2 = (uint32_t)__builtin_amdgcn_readlane((int)s30.z, k);
                    a3 = (uint32_t)__builtin_amdgcn_readlane((int)s30.w, k);
                    a4 = (uint32_t)__builtin_amdgcn_readlane((int)s31.x, k);
                    a5 = (uint32_t)__builtin_amdgcn_readlane((int)s31.y, k);
                    a6 = (uint32_t)__builtin_amdgcn_readlane((int)s31.z, k);
                    a7 = (uint32_t)__builtin_amdgcn_readlane((int)s31.w, k);
                }
                w0 &= ~(((uint64_t)a1 << 32) | (uint64_t)a0);   // forward kills
                w1 &= ~(((uint64_t)a3 << 32) | (uint64_t)a2);
                w2 &= ~(((uint64_t)a5 << 32) | (uint64_t)a4);
                w3 &= ~(((uint64_t)a7 << 32) | (uint64_t)a6);
            }
            uint32_t n0 = (uint32_t)__popcll(sv0), n1 = (uint32_t)__popcll(sv1);
            uint32_t n2 = (uint32_t)__popcll(sv2), n3 = (uint32_t)__popcll(sv3);
            uint32_t o1 = n0, o2 = n0 + n1, o3 = n0 + n1 + n2, ns = o3 + n3;
            if (tid == 0) {
                svL[8*c+0] = (uint32_t)sv0; svL[8*c+1] = (uint32_t)(sv0 >> 32);
                svL[8*c+2] = (uint32_t)sv1; svL[8*c+3] = (uint32_t)(sv1 >> 32);
                svL[8*c+4] = (uint32_t)sv2; svL[8*c+5] = (uint32_t)(sv2 >> 32);
                svL[8*c+6] = (uint32_t)sv3; svL[8*c+7] = (uint32_t)(sv3 >> 32);
                nsSh = ns;
            }
            uint64_t lowm = (1ull << tid) - 1ull;       // tid < 64
            if ((sv0 >> tid) & 1ull) sidx[      __popcll(sv0 & lowm)] = (uint32_t)(base + tid);
            if ((sv1 >> tid) & 1ull) sidx[o1 +  __popcll(sv1 & lowm)] = (uint32_t)(base + 64 + tid);
            if ((sv2 >> tid) & 1ull) sidx[o2 +  __popcll(sv2 & lowm)] = (uint32_t)(base + 128 + tid);
            if ((sv3 >> tid) & 1ull) sidx[o3 +  __popcll(sv3 & lowm)] = (uint32_t)(base + 192 + tid);
            if (ns) {                 // pad to x32 with first survivor (OR-idempotent)
                uint32_t nsPad = (ns + 31u) & ~31u;     // <= 256
                uint32_t first;
                if      (sv0) first = (uint32_t)base +       (uint32_t)(__ffsll((unsigned long long)sv0) - 1);
                else if (sv1) first = (uint32_t)base + 64u + (uint32_t)(__ffsll((unsigned long long)sv1) - 1);
                else if (sv2) first = (uint32_t)base + 128u+ (uint32_t)(__ffsll((unsigned long long)sv2) - 1);
                else          first = (uint32_t)base + 192u+ (uint32_t)(__ffsll((unsigned long long)sv3) - 1);
                #pragma unroll
                for (int rr = 0; rr < 4; rr++) {
                    uint32_t ii = (uint32_t)tid + 64u * rr;
                    if (ii >= ns && ii < nsPad) sidx[ii] = first;
                }
            }
            if (c + 1 < NCH) {        // prefetch next chunk rows (overlaps OR phase)
                const uint32_t* p0 = mask + (size_t)(base + 256 + tid) * MW + 8*(c+1);
                s00 = *(const uint4*)p0;  s01 = *(const uint4*)(p0 + 4);
                const uint32_t* p1 = p0 + (size_t)64 * MW;
                s10 = *(const uint4*)p1;  s11 = *(const uint4*)(p1 + 4);
                const uint32_t* p2 = p1 + (size_t)64 * MW;
                s20 = *(const uint4*)p2;  s21 = *(const uint4*)(p2 + 4);
                const uint32_t* p3 = p2 + (size_t)64 * MW;
                s30 = *(const uint4*)p3;  s31 = *(const uint4*)(p3 + 4);
            }
        }
        __syncthreads();
        int w = tid - 64;
        if (w >= 0 && w < MW) {
            uint32_t nsPad = (nsSh + 31u) & ~31u;
            uint32_t acc = rem[w];
            for (uint32_t t2 = 0; t2 < nsPad; t2 += 32) {
                uint32_t r[32];
                #pragma unroll
                for (int q = 0; q < 32; q++)
                    r[q] = mask[(size_t)sidx[t2 + q] * MW + w];
                uint32_t o = 0u;
                #pragma unroll
                for (int q = 0; q < 32; q++) o |= r[q];
                acc |= o;
            }
            rem[w] = acc;
        }
        __syncthreads();
    }
    // final validity + emit first 300 (tail already zeroed above)
    if (tid < MW) {
        uint32_t vv = svL[tid] & ~rem[tid];
        if (tid == MW - 1) vv &= 0xFFFFu;
        rem[tid] = vv;
    }
    __syncthreads();
    if (tid == 0) {
        uint32_t run = 0;
        for (int w2 = 0; w2 < MW; w2++) { pref[w2] = run; run += (uint32_t)__popc(rem[w2]); }
    }
    __syncthreads();
    if (tid < MW) {
        uint32_t b = rem[tid];
        uint32_t r = pref[tid];
        int basebit = tid * 32;
        while (b && r < K_POST) {
            int bit = __ffs(b) - 1;
            b &= b - 1u;
            float4 pp = OP[basebit + bit];
            *(float4*)(out + (size_t)r * 4) = pp;
            r++;
        }
    }
}

extern "C" void kernel_launch(void* const* d_in, const int* in_sizes, int n_in,
                              void* d_out, int out_size, void* d_ws, size_t ws_size,
                              hipStream_t stream) {
    (void)in_sizes; (void)n_in; (void)out_size; (void)ws_size;
    const float* scores = (const float*)d_in[0];
    const float* deltas = (const float*)d_in[1];
    float* out = (float*)d_out;

    char* ws = (char*)d_ws;
    size_t off = 0;
    auto alloc = [&](size_t bytes) -> void* {
        void* p = ws + off;
        off += (bytes + 255) & ~(size_t)255;
        return p;
    };
    uint32_t* keys  = (uint32_t*)alloc((size_t)N_TOT * 4);
    uint64_t* cand  = (uint64_t*)alloc((size_t)CAP * 8);
    float4*   P     = (float4*)alloc((size_t)K_PRE * 16);
    uint64_t* yk    = (uint64_t*)alloc((size_t)K_PRE * 8);
    float4*   OP    = (float4*)alloc((size_t)K_PRE * 16);
    float4*   Q     = (float4*)alloc((size_t)K_PRE * 16);
    float*    Bnd   = (float*)alloc((size_t)K_PRE * 4);
    // +256B slack: last-chunk segment loads read 4 words past row end
    uint32_t* mask  = (uint32_t*)alloc((size_t)ROWS_PAD * MW * 4 + 256);

    k_keys_hist<<<N_TOT / 1024, 256, 0, stream>>>(scores, deltas, keys);
    k_findbin_compact<<<N_TOT / 1024, 256, 0, stream>>>(keys, cand);
    k_rank_props<<<1024, 256, 0, stream>>>(cand, deltas, P, yk);
    k_rank_y2<<<K_PRE / G, 256, 0, stream>>>(yk, P, OP, Q, Bnd);
    k_mask<<<dim3(ROWB, COLB), 256, 0, stream>>>(Q, Bnd, mask);
    k_scan<<<1, 256, 0, stream>>>(mask, OP, out);
}